// Round 1
// baseline (932.557 us; speedup 1.0000x reference)
//
#include <hip/hip_runtime.h>

#define N_NODES 100000
#define N_EDGES 1600000
#define IN_C 256
#define HID 128
#define NEG_SLOPE 0.2f
#define BN_EPS 1e-5f

__device__ __forceinline__ float lrelu(float x) { return x > 0.f ? x : NEG_SLOPE * x; }

// ---------------- init: zero atomics targets ----------------
__global__ void k_init(int* __restrict__ counts, int* __restrict__ cursor,
                       float* __restrict__ bnacc) {
    int i = blockIdx.x * 256 + threadIdx.x;
    if (i < N_NODES) { counts[i] = 0; cursor[i] = 0; }
    if (i < 512) bnacc[i] = 0.f;
}

// ---------------- SGEMM: out[N,128] = A[N,K] @ W[K,128] (+bias) ----------------
// BM=64 nodes, BN=128 ch, BK=64. 256 threads: cg=t&31 -> 4 ch, ng=t>>5 -> 8 nodes.
__global__ __launch_bounds__(256) void k_sgemm(const float* __restrict__ A,
                                               const float* __restrict__ W,
                                               const float* __restrict__ bias,
                                               float* __restrict__ out, int K) {
    __shared__ float xs[64 * 68];   // [k][n], stride 68 keeps 16B alignment
    __shared__ float Ws[64 * 128];  // [k][ch]
    const int t = threadIdx.x;
    const int n0 = blockIdx.x * 64;
    const int cg = t & 31, ng = t >> 5;
    const int ch4 = cg * 4, n8 = ng * 8;
    float acc[8][4];
#pragma unroll
    for (int i = 0; i < 8; ++i)
#pragma unroll
        for (int j = 0; j < 4; ++j) acc[i][j] = 0.f;

    for (int kc = 0; kc < K; kc += 64) {
        for (int i = t; i < 4096; i += 256) {
            int n = i >> 6, kk = i & 63;
            int gn = n0 + n;
            float v = (gn < N_NODES) ? A[(size_t)gn * K + kc + kk] : 0.f;
            xs[kk * 68 + n] = v;
        }
        for (int i = t; i < 8192; i += 256) Ws[i] = W[(size_t)kc * 128 + i];
        __syncthreads();
#pragma unroll 4
        for (int kk = 0; kk < 64; ++kk) {
            const float4 wv = *(const float4*)&Ws[kk * 128 + ch4];
            const float4 xa = *(const float4*)&xs[kk * 68 + n8];
            const float4 xb = *(const float4*)&xs[kk * 68 + n8 + 4];
            const float xv[8] = {xa.x, xa.y, xa.z, xa.w, xb.x, xb.y, xb.z, xb.w};
            const float wq[4] = {wv.x, wv.y, wv.z, wv.w};
#pragma unroll
            for (int i = 0; i < 8; ++i)
#pragma unroll
                for (int j = 0; j < 4; ++j) acc[i][j] += xv[i] * wq[j];
        }
        __syncthreads();
    }
    float4 bv = make_float4(0.f, 0.f, 0.f, 0.f);
    if (bias) bv = *(const float4*)&bias[ch4];
#pragma unroll
    for (int i = 0; i < 8; ++i) {
        int gn = n0 + n8 + i;
        if (gn < N_NODES) {
            float4 r;
            r.x = acc[i][0] + bv.x; r.y = acc[i][1] + bv.y;
            r.z = acc[i][2] + bv.z; r.w = acc[i][3] + bv.w;
            *(float4*)&out[(size_t)gn * 128 + ch4] = r;
        }
    }
}

// ---------------- attention coefficients per node/head ----------------
// att_src[h][c'] flat == channel index c (c = h*32 + c')
__global__ __launch_bounds__(256) void k_att(const float* __restrict__ h,
                                             const float* __restrict__ att_s,
                                             const float* __restrict__ att_d,
                                             float* __restrict__ a_src,
                                             float* __restrict__ a_dst) {
    int node = blockIdx.x * 2 + (threadIdx.x >> 7);
    int c = threadIdx.x & 127;
    float hv = h[(size_t)node * 128 + c];
    float ps = hv * att_s[c];
    float pd = hv * att_d[c];
#pragma unroll
    for (int m = 1; m < 32; m <<= 1) {
        ps += __shfl_xor(ps, m);
        pd += __shfl_xor(pd, m);
    }
    if ((c & 31) == 0) {
        int head = c >> 5;
        a_src[node * 4 + head] = ps;
        a_dst[node * 4 + head] = pd;
    }
}

// ---------------- CSR build ----------------
__global__ void k_hist(const int* __restrict__ ei, int* __restrict__ counts) {
    int e = blockIdx.x * 256 + threadIdx.x;
    if (e < N_EDGES) atomicAdd(&counts[ei[N_EDGES + e]], 1);
}

__global__ __launch_bounds__(256) void k_scan_a(const int* __restrict__ counts,
                                                int* __restrict__ row_ptr,
                                                int* __restrict__ bsums) {
    __shared__ int sh[256];
    int t = threadIdx.x;
    int base = blockIdx.x * 1024 + t * 4;
    int4 v = make_int4(0, 0, 0, 0);
    if (base + 3 < N_NODES) v = *(const int4*)&counts[base];
    else {
        if (base + 0 < N_NODES) v.x = counts[base + 0];
        if (base + 1 < N_NODES) v.y = counts[base + 1];
        if (base + 2 < N_NODES) v.z = counts[base + 2];
        if (base + 3 < N_NODES) v.w = counts[base + 3];
    }
    int tsum = v.x + v.y + v.z + v.w;
    sh[t] = tsum;
    __syncthreads();
    int val = tsum;
    for (int off = 1; off < 256; off <<= 1) {
        int other = (t >= off) ? sh[t - off] : 0;
        __syncthreads();
        val += other;
        sh[t] = val;
        __syncthreads();
    }
    int run = val - tsum;  // exclusive within block
    if (base + 0 < N_NODES) row_ptr[base + 0] = run; run += v.x;
    if (base + 1 < N_NODES) row_ptr[base + 1] = run; run += v.y;
    if (base + 2 < N_NODES) row_ptr[base + 2] = run; run += v.z;
    if (base + 3 < N_NODES) row_ptr[base + 3] = run;
    if (t == 255) bsums[blockIdx.x] = val;
}

__global__ void k_scan_b(const int* __restrict__ bsums, int* __restrict__ boffs,
                         int* __restrict__ row_ptr, int nb) {
    if (threadIdx.x == 0 && blockIdx.x == 0) {
        int run = 0;
        for (int b = 0; b < nb; ++b) { boffs[b] = run; run += bsums[b]; }
        row_ptr[N_NODES] = run;
    }
}

__global__ void k_scan_c(int* __restrict__ row_ptr, const int* __restrict__ boffs) {
    int base = blockIdx.x * 1024 + threadIdx.x * 4;
    int off = boffs[blockIdx.x];
#pragma unroll
    for (int i = 0; i < 4; ++i) {
        int idx = base + i;
        if (idx < N_NODES) row_ptr[idx] += off;
    }
}

__global__ void k_scatter(const int* __restrict__ ei, const int* __restrict__ row_ptr,
                          int* __restrict__ cursor, int* __restrict__ sorted_src) {
    int e = blockIdx.x * 256 + threadIdx.x;
    if (e < N_EDGES) {
        int s = ei[e], d = ei[N_EDGES + e];
        int pos = row_ptr[d] + atomicAdd(&cursor[d], 1);
        sorted_src[pos] = s;
    }
}

// ---------------- GAT aggregate: one wave per dst node ----------------
// alpha = exp(e)/sum(exp(e))  (identical to max-subtracted softmax; e <= ~9, no overflow)
__global__ __launch_bounds__(256) void k_gat_aggregate(
    const float* __restrict__ h, const float* __restrict__ a_src,
    const float* __restrict__ a_dst, const int* __restrict__ row_ptr,
    const int* __restrict__ sorted_src, const float* __restrict__ bias,
    float* __restrict__ out1) {
    int lane = threadIdx.x & 63;
    int node = (blockIdx.x << 2) + (threadIdx.x >> 6);
    if (node >= N_NODES) return;
    int start = row_ptr[node];
    int deg = row_ptr[node + 1] - start;
    int c0 = lane * 2;
    if (deg == 0) {
        float2 b = *(const float2*)&bias[c0];
        *(float2*)&out1[(size_t)node * 128 + c0] = b;
        return;
    }
    float4 ad = *(const float4*)&a_dst[node * 4];
    float p0 = 0.f, p1 = 0.f, p2 = 0.f, p3 = 0.f;
    for (int j = lane; j < deg; j += 64) {
        int s = sorted_src[start + j];
        float4 as = *(const float4*)&a_src[s * 4];
        p0 += __expf(lrelu(as.x + ad.x));
        p1 += __expf(lrelu(as.y + ad.y));
        p2 += __expf(lrelu(as.z + ad.z));
        p3 += __expf(lrelu(as.w + ad.w));
    }
#pragma unroll
    for (int m = 1; m < 64; m <<= 1) {
        p0 += __shfl_xor(p0, m); p1 += __shfl_xor(p1, m);
        p2 += __shfl_xor(p2, m); p3 += __shfl_xor(p3, m);
    }
    int head = lane >> 4;  // channel c0=2*lane -> head = c0/32
    float adh = head == 0 ? ad.x : head == 1 ? ad.y : head == 2 ? ad.z : ad.w;
    float den = head == 0 ? p0 : head == 1 ? p1 : head == 2 ? p2 : p3;
    float rden = 1.f / den;
    float acc0 = 0.f, acc1 = 0.f;
    for (int j0 = 0; j0 < deg; j0 += 64) {
        int nj = min(64, deg - j0);
        int sj = (j0 + lane < deg) ? sorted_src[start + j0 + lane] : 0;
        for (int jj = 0; jj < nj; ++jj) {
            int s = __shfl(sj, jj);
            float e = lrelu(a_src[s * 4 + head] + adh);
            float alpha = __expf(e) * rden;
            float2 hv = *(const float2*)&h[(size_t)s * 128 + c0];
            acc0 += alpha * hv.x;
            acc1 += alpha * hv.y;
        }
    }
    float2 b = *(const float2*)&bias[c0];
    *(float2*)&out1[(size_t)node * 128 + c0] = make_float2(acc0 + b.x, acc1 + b.y);
}

// ---------------- GIN aggregate: z = (1+eps)*out1 + sum_{in} out1[src] ----------------
__global__ __launch_bounds__(256) void k_gin_aggregate(
    const float* __restrict__ out1f, const int* __restrict__ row_ptr,
    const int* __restrict__ sorted_src, const float* __restrict__ eps_ptr,
    float* __restrict__ z) {
    int lane = threadIdx.x & 63;
    int node = (blockIdx.x << 2) + (threadIdx.x >> 6);
    if (node >= N_NODES) return;
    int start = row_ptr[node];
    int deg = row_ptr[node + 1] - start;
    int c0 = lane * 2;
    float acc0 = 0.f, acc1 = 0.f;
    for (int j0 = 0; j0 < deg; j0 += 64) {
        int nj = min(64, deg - j0);
        int sj = (j0 + lane < deg) ? sorted_src[start + j0 + lane] : 0;
        for (int jj = 0; jj < nj; ++jj) {
            int s = __shfl(sj, jj);
            float2 v = *(const float2*)&out1f[(size_t)s * 128 + c0];
            acc0 += v.x;
            acc1 += v.y;
        }
    }
    float ep = 1.f + eps_ptr[0];
    float2 own = *(const float2*)&out1f[(size_t)node * 128 + c0];
    *(float2*)&z[(size_t)node * 128 + c0] =
        make_float2(ep * own.x + acc0, ep * own.y + acc1);
}

// ---------------- BN stats: per-channel sum + sumsq ----------------
__global__ __launch_bounds__(256) void k_bnstats(const float* __restrict__ buf,
                                                 float* __restrict__ acc) {
    __shared__ float sh[512];
    int t = threadIdx.x;
    int c = t & 127;
    float s = 0.f, s2 = 0.f;
    for (int r = blockIdx.x * 2 + (t >> 7); r < N_NODES; r += gridDim.x * 2) {
        float v = buf[(size_t)r * 128 + c];
        s += v;
        s2 += v * v;
    }
    sh[t] = s;
    sh[256 + t] = s2;
    __syncthreads();
    if (t < 128) {
        atomicAdd(&acc[c], sh[t] + sh[t + 128]);
        atomicAdd(&acc[128 + c], sh[256 + t] + sh[256 + t + 128]);
    }
}

__global__ void k_bnparams(const float* __restrict__ acc, const float* __restrict__ gamma,
                           const float* __restrict__ beta, float* __restrict__ ss) {
    int c = threadIdx.x;
    if (c < 128) {
        float mu = acc[c] * (1.f / N_NODES);
        float var = acc[128 + c] * (1.f / N_NODES) - mu * mu;
        float rs = rsqrtf(var + BN_EPS);
        float sc = rs * gamma[c];
        ss[c] = sc;
        ss[128 + c] = beta[c] - mu * sc;
    }
}

// ---------------- apply BN (scale/shift) + ELU, in place ----------------
__global__ __launch_bounds__(256) void k_bn_elu(float* __restrict__ buf,
                                                const float* __restrict__ ss) {
    size_t i = (size_t)blockIdx.x * 256 + threadIdx.x;  // float4 index
    if (i >= (size_t)N_NODES * 32) return;
    int c4 = (int)(i & 31) * 4;
    float4 v = *(float4*)&buf[i * 4];
    float4 sc = *(const float4*)&ss[c4];
    float4 sh = *(const float4*)&ss[128 + c4];
    float r0 = v.x * sc.x + sh.x;
    float r1 = v.y * sc.y + sh.y;
    float r2 = v.z * sc.z + sh.z;
    float r3 = v.w * sc.w + sh.w;
    r0 = r0 > 0.f ? r0 : __expf(r0) - 1.f;
    r1 = r1 > 0.f ? r1 : __expf(r1) - 1.f;
    r2 = r2 > 0.f ? r2 : __expf(r2) - 1.f;
    r3 = r3 > 0.f ? r3 : __expf(r3) - 1.f;
    *(float4*)&buf[i * 4] = make_float4(r0, r1, r2, r3);
}

extern "C" void kernel_launch(void* const* d_in, const int* in_sizes, int n_in,
                              void* d_out, int out_size, void* d_ws, size_t ws_size,
                              hipStream_t stream) {
    (void)in_sizes; (void)n_in; (void)out_size; (void)ws_size;
    const float* x        = (const float*)d_in[0];
    const float* W_gat    = (const float*)d_in[1];
    const float* att_src  = (const float*)d_in[2];
    const float* att_dst  = (const float*)d_in[3];
    const float* bias_gat = (const float*)d_in[4];
    const float* bn1_g    = (const float*)d_in[5];
    const float* bn1_b    = (const float*)d_in[6];
    const float* eps_gin  = (const float*)d_in[7];
    const float* lin_W    = (const float*)d_in[8];
    const float* lin_b    = (const float*)d_in[9];
    const float* bn2_g    = (const float*)d_in[10];
    const float* bn2_b    = (const float*)d_in[11];
    const int*   ei       = (const int*)d_in[12];
    float* out = (float*)d_out;

    char* w = (char*)d_ws;
    size_t o = 0;
    auto take = [&](size_t b) -> char* {
        char* p = w + o;
        o += (b + 255) & ~(size_t)255;
        return p;
    };
    float* h       = (float*)take((size_t)N_NODES * 128 * 4);
    float* out1    = (float*)take((size_t)N_NODES * 128 * 4);
    float* a_src   = (float*)take((size_t)N_NODES * 4 * 4);
    float* a_dst   = (float*)take((size_t)N_NODES * 4 * 4);
    int*   sorted  = (int*)take((size_t)N_EDGES * 4);
    int*   row_ptr = (int*)take((size_t)(N_NODES + 1) * 4);
    int*   counts  = (int*)take((size_t)N_NODES * 4);
    int*   cursor  = (int*)take((size_t)N_NODES * 4);
    int*   bsums   = (int*)take(4096);
    int*   boffs   = (int*)take(4096);
    float* bnacc   = (float*)take(512 * 4);
    float* ss1     = (float*)take(256 * 4);
    float* ss2     = (float*)take(256 * 4);
    float* z = h;  // reuse: h dead after k_gat_aggregate

    const int nScanBlocks = (N_NODES + 1023) / 1024;

    k_init<<<(N_NODES + 255) / 256, 256, 0, stream>>>(counts, cursor, bnacc);
    k_sgemm<<<(N_NODES + 63) / 64, 256, 0, stream>>>(x, W_gat, nullptr, h, IN_C);
    k_att<<<N_NODES / 2, 256, 0, stream>>>(h, att_src, att_dst, a_src, a_dst);
    k_hist<<<(N_EDGES + 255) / 256, 256, 0, stream>>>(ei, counts);
    k_scan_a<<<nScanBlocks, 256, 0, stream>>>(counts, row_ptr, bsums);
    k_scan_b<<<1, 64, 0, stream>>>(bsums, boffs, row_ptr, nScanBlocks);
    k_scan_c<<<nScanBlocks, 256, 0, stream>>>(row_ptr, boffs);
    k_scatter<<<(N_EDGES + 255) / 256, 256, 0, stream>>>(ei, row_ptr, cursor, sorted);
    k_gat_aggregate<<<N_NODES / 4, 256, 0, stream>>>(h, a_src, a_dst, row_ptr, sorted,
                                                     bias_gat, out1);
    k_bnstats<<<512, 256, 0, stream>>>(out1, bnacc);
    k_bnparams<<<1, 128, 0, stream>>>(bnacc, bn1_g, bn1_b, ss1);
    k_bn_elu<<<N_NODES * 32 / 256, 256, 0, stream>>>(out1, ss1);
    k_gin_aggregate<<<N_NODES / 4, 256, 0, stream>>>(out1, row_ptr, sorted, eps_gin, z);
    k_sgemm<<<(N_NODES + 63) / 64, 256, 0, stream>>>(z, lin_W, lin_b, out, HID);
    k_bnstats<<<512, 256, 0, stream>>>(out, bnacc + 256);
    k_bnparams<<<1, 128, 0, stream>>>(bnacc + 256, bn2_g, bn2_b, ss2);
    k_bn_elu<<<N_NODES * 32 / 256, 256, 0, stream>>>(out, ss2);
}

// Round 2
// 666.400 us; speedup vs baseline: 1.3994x; 1.3994x over previous
//
#include <hip/hip_runtime.h>

#define N_NODES 100000
#define N_EDGES 1600000
#define IN_C 256
#define HID 128
#define NEG_SLOPE 0.2f
#define BN_EPS 1e-5f

typedef unsigned int uint32;
typedef unsigned short ushort16;
typedef __attribute__((ext_vector_type(8))) short bf16x8;
typedef __attribute__((ext_vector_type(4))) float f32x4;

__device__ __forceinline__ float lrelu(float x) { return x > 0.f ? x : NEG_SLOPE * x; }

__device__ __forceinline__ unsigned short f2bf(float f) {
    uint32 u = __float_as_uint(f);
    u += 0x7fffu + ((u >> 16) & 1u);
    return (unsigned short)(u >> 16);
}
__device__ __forceinline__ float bf2f(unsigned short h) {
    return __uint_as_float(((uint32)h) << 16);
}

// ---------------- init ----------------
__global__ void k_init(int* __restrict__ counts, int* __restrict__ cursor,
                       float* __restrict__ bnacc) {
    int i = blockIdx.x * 256 + threadIdx.x;
    if (i < N_NODES) { counts[i] = 0; cursor[i] = 0; }
    if (i < 512) bnacc[i] = 0.f;
}

// ---------------- transpose W [K][128] fp32 -> Wt [128][K] bf16 ----------------
__global__ void k_transpose_bf16(const float* __restrict__ W, unsigned short* __restrict__ Wt,
                                 int K) {
    int idx = blockIdx.x * 256 + threadIdx.x;
    if (idx >= K * 128) return;
    int k = idx >> 7, n = idx & 127;
    Wt[n * K + k] = f2bf(W[idx]);
}

// ---------------- MFMA GEMM: Out[M,128] = A[M,K] @ W[K,128] ----------------
// Wt is [n][k] bf16. 128x128 tile, 256 threads = 4 waves (2x2 of 64x64).
template <bool AF32, bool OUTF32>
__global__ __launch_bounds__(256) void k_gemm(const void* __restrict__ Av,
                                              const unsigned short* __restrict__ Wt,
                                              void* __restrict__ Out, int K) {
    __shared__ unsigned short As[128 * 72];  // [m][k] pad 72 (144B rows)
    __shared__ unsigned short Bs[128 * 72];  // [n][k]
    const int t = threadIdx.x;
    const int n0 = blockIdx.x * 128;
    const int wv = t >> 6, lane = t & 63;
    const int wy = wv >> 1, wx = wv & 1;
    const int lm = lane & 15, lg = lane >> 4;

    f32x4 acc[4][4];
#pragma unroll
    for (int i = 0; i < 4; ++i)
#pragma unroll
        for (int j = 0; j < 4; ++j) acc[i][j] = (f32x4){0.f, 0.f, 0.f, 0.f};

    for (int kc = 0; kc < K; kc += 64) {
        if (AF32) {
            const float* A = (const float*)Av;
#pragma unroll
            for (int p = 0; p < 8; ++p) {
                int idx = p * 256 + t;
                int row = idx >> 4, c4 = idx & 15;
                int gn = n0 + row;
                float4 v = make_float4(0.f, 0.f, 0.f, 0.f);
                if (gn < N_NODES) v = *(const float4*)&A[(size_t)gn * K + kc + c4 * 4];
                ushort4 b;
                b.x = f2bf(v.x); b.y = f2bf(v.y); b.z = f2bf(v.z); b.w = f2bf(v.w);
                *(ushort4*)&As[row * 72 + c4 * 4] = b;
            }
        } else {
            const unsigned short* A = (const unsigned short*)Av;
#pragma unroll
            for (int p = 0; p < 4; ++p) {
                int idx = p * 256 + t;
                int row = idx >> 3, c = idx & 7;
                int gn = n0 + row;
                uint4 v = make_uint4(0, 0, 0, 0);
                if (gn < N_NODES) v = *(const uint4*)&A[(size_t)gn * K + kc + c * 8];
                *(uint4*)&As[row * 72 + c * 8] = v;
            }
        }
#pragma unroll
        for (int p = 0; p < 4; ++p) {
            int idx = p * 256 + t;
            int n = idx >> 3, c = idx & 7;
            uint4 v = *(const uint4*)&Wt[(size_t)n * K + kc + c * 8];
            *(uint4*)&Bs[n * 72 + c * 8] = v;
        }
        __syncthreads();
#pragma unroll
        for (int ks = 0; ks < 2; ++ks) {
            bf16x8 af[4], bfr[4];
#pragma unroll
            for (int i = 0; i < 4; ++i)
                af[i] = *(const bf16x8*)&As[(wy * 64 + i * 16 + lm) * 72 + ks * 32 + lg * 8];
#pragma unroll
            for (int j = 0; j < 4; ++j)
                bfr[j] = *(const bf16x8*)&Bs[(wx * 64 + j * 16 + lm) * 72 + ks * 32 + lg * 8];
#pragma unroll
            for (int i = 0; i < 4; ++i)
#pragma unroll
                for (int j = 0; j < 4; ++j)
                    acc[i][j] = __builtin_amdgcn_mfma_f32_16x16x32_bf16(af[i], bfr[j],
                                                                        acc[i][j], 0, 0, 0);
        }
        __syncthreads();
    }
    // epilogue: D row = (lane>>4)*4 + reg, col = lane&15
#pragma unroll
    for (int i = 0; i < 4; ++i) {
#pragma unroll
        for (int r = 0; r < 4; ++r) {
            int row = n0 + wy * 64 + i * 16 + lg * 4 + r;
            if (row < N_NODES) {
#pragma unroll
                for (int j = 0; j < 4; ++j) {
                    int col = wx * 64 + j * 16 + lm;
                    float v = acc[i][j][r];
                    if (OUTF32) ((float*)Out)[(size_t)row * 128 + col] = v;
                    else ((unsigned short*)Out)[(size_t)row * 128 + col] = f2bf(v);
                }
            }
        }
    }
}

// ---------------- attention coefficients ----------------
__global__ __launch_bounds__(256) void k_att(const unsigned short* __restrict__ hb,
                                             const float* __restrict__ att_s,
                                             const float* __restrict__ att_d,
                                             float* __restrict__ a_src,
                                             float* __restrict__ a_dst) {
    int node = blockIdx.x * 2 + (threadIdx.x >> 7);
    int c = threadIdx.x & 127;
    float hv = bf2f(hb[(size_t)node * 128 + c]);
    float ps = hv * att_s[c];
    float pd = hv * att_d[c];
#pragma unroll
    for (int m = 1; m < 32; m <<= 1) {
        ps += __shfl_xor(ps, m);
        pd += __shfl_xor(pd, m);
    }
    if ((c & 31) == 0) {
        int head = c >> 5;
        a_src[node * 4 + head] = ps;
        a_dst[node * 4 + head] = pd;
    }
}

// ---------------- CSR build ----------------
__global__ void k_hist(const int* __restrict__ ei, int* __restrict__ counts) {
    int e = blockIdx.x * 256 + threadIdx.x;
    if (e < N_EDGES) atomicAdd(&counts[ei[N_EDGES + e]], 1);
}

__global__ __launch_bounds__(256) void k_scan_a(const int* __restrict__ counts,
                                                int* __restrict__ row_ptr,
                                                int* __restrict__ bsums) {
    __shared__ int sh[256];
    int t = threadIdx.x;
    int base = blockIdx.x * 1024 + t * 4;
    int4 v = make_int4(0, 0, 0, 0);
    if (base + 3 < N_NODES) v = *(const int4*)&counts[base];
    else {
        if (base + 0 < N_NODES) v.x = counts[base + 0];
        if (base + 1 < N_NODES) v.y = counts[base + 1];
        if (base + 2 < N_NODES) v.z = counts[base + 2];
        if (base + 3 < N_NODES) v.w = counts[base + 3];
    }
    int tsum = v.x + v.y + v.z + v.w;
    sh[t] = tsum;
    __syncthreads();
    int val = tsum;
    for (int off = 1; off < 256; off <<= 1) {
        int other = (t >= off) ? sh[t - off] : 0;
        __syncthreads();
        val += other;
        sh[t] = val;
        __syncthreads();
    }
    int run = val - tsum;
    if (base + 0 < N_NODES) row_ptr[base + 0] = run; run += v.x;
    if (base + 1 < N_NODES) row_ptr[base + 1] = run; run += v.y;
    if (base + 2 < N_NODES) row_ptr[base + 2] = run; run += v.z;
    if (base + 3 < N_NODES) row_ptr[base + 3] = run;
    if (t == 255) bsums[blockIdx.x] = val;
}

// single wave, nb <= 128
__global__ void k_scan_b(const int* __restrict__ bsums, int* __restrict__ boffs,
                         int* __restrict__ row_ptr, int nb) {
    int lane = threadIdx.x;
    int o0 = (lane < nb) ? bsums[lane] : 0;
    int o1 = (64 + lane < nb) ? bsums[64 + lane] : 0;
    int v0 = o0, v1 = o1;
#pragma unroll
    for (int off = 1; off < 64; off <<= 1) {
        int t0 = __shfl_up(v0, off);
        int t1 = __shfl_up(v1, off);
        if (lane >= off) { v0 += t0; v1 += t1; }
    }
    int tot0 = __shfl(v0, 63);
    if (lane < nb) boffs[lane] = v0 - o0;
    if (64 + lane < nb) boffs[64 + lane] = tot0 + v1 - o1;
    if (lane == 63) row_ptr[N_NODES] = tot0 + v1;
}

__global__ void k_scan_c(int* __restrict__ row_ptr, const int* __restrict__ boffs) {
    int base = blockIdx.x * 1024 + threadIdx.x * 4;
    int off = boffs[blockIdx.x];
#pragma unroll
    for (int i = 0; i < 4; ++i) {
        int idx = base + i;
        if (idx < N_NODES) row_ptr[idx] += off;
    }
}

// ---------------- scatter + edge weight ----------------
__global__ void k_scatter_w(const int* __restrict__ ei, const int* __restrict__ row_ptr,
                            int* __restrict__ cursor, const float* __restrict__ a_src,
                            const float* __restrict__ a_dst, int* __restrict__ sorted_src,
                            float4* __restrict__ wsorted) {
    int e = blockIdx.x * 256 + threadIdx.x;
    if (e >= N_EDGES) return;
    int s = ei[e], d = ei[N_EDGES + e];
    int pos = row_ptr[d] + atomicAdd(&cursor[d], 1);
    sorted_src[pos] = s;
    float4 as = *(const float4*)&a_src[s * 4];
    float4 ad = *(const float4*)&a_dst[d * 4];
    float4 w;
    w.x = __expf(lrelu(as.x + ad.x));
    w.y = __expf(lrelu(as.y + ad.y));
    w.z = __expf(lrelu(as.z + ad.z));
    w.w = __expf(lrelu(as.w + ad.w));
    wsorted[pos] = w;
}

// ---------------- GAT aggregate: one wave per dst node ----------------
__global__ __launch_bounds__(256) void k_gat_agg(const uint32* __restrict__ hb32,
                                                 const int* __restrict__ row_ptr,
                                                 const int* __restrict__ sorted_src,
                                                 const float4* __restrict__ wsorted,
                                                 float* __restrict__ out1) {
    __shared__ int sbuf[4][64];
    __shared__ float4 wbuf[4][64];
    int lane = threadIdx.x & 63, wv = threadIdx.x >> 6;
    int node = blockIdx.x * 4 + wv;
    int start = row_ptr[node];
    int deg = row_ptr[node + 1] - start;
    if (deg == 0) {
        *(float2*)&out1[(size_t)node * 128 + lane * 2] = make_float2(0.f, 0.f);
        return;
    }
    float4 den = make_float4(0.f, 0.f, 0.f, 0.f);
    for (int j = lane; j < deg; j += 64) {
        float4 w = wsorted[start + j];
        den.x += w.x; den.y += w.y; den.z += w.z; den.w += w.w;
    }
#pragma unroll
    for (int m = 1; m < 64; m <<= 1) {
        den.x += __shfl_xor(den.x, m);
        den.y += __shfl_xor(den.y, m);
        den.z += __shfl_xor(den.z, m);
        den.w += __shfl_xor(den.w, m);
    }
    int head = lane >> 4;
    float dh = head == 0 ? den.x : head == 1 ? den.y : head == 2 ? den.z : den.w;
    float rden = 1.f / dh;
    const float* wS = (const float*)&wbuf[wv][0];
    float acc0 = 0.f, acc1 = 0.f;
    int s_pad = sorted_src[start];
    for (int j0 = 0; j0 < deg; j0 += 64) {
        int j = j0 + lane;
        int s = s_pad;
        float4 w = make_float4(0.f, 0.f, 0.f, 0.f);
        if (j < deg) { s = sorted_src[start + j]; w = wsorted[start + j]; }
        sbuf[wv][lane] = s;
        wbuf[wv][lane] = w;
        __builtin_amdgcn_wave_barrier();
        int nj8 = min(64, deg - j0);
        nj8 = (nj8 + 7) & ~7;
        for (int jj = 0; jj < nj8; jj += 8) {
#pragma unroll
            for (int u = 0; u < 8; ++u) {
                int ss = sbuf[wv][jj + u];
                float wh = wS[(jj + u) * 4 + head];
                uint32 hv = hb32[(size_t)ss * 64 + lane];
                acc0 += wh * __uint_as_float(hv << 16);
                acc1 += wh * __uint_as_float(hv & 0xffff0000u);
            }
        }
        __builtin_amdgcn_wave_barrier();
    }
    acc0 *= rden;
    acc1 *= rden;
    *(float2*)&out1[(size_t)node * 128 + lane * 2] = make_float2(acc0, acc1);
}

// ---------------- GIN aggregate ----------------
__global__ __launch_bounds__(256) void k_gin_agg(const uint32* __restrict__ ob32,
                                                 const int* __restrict__ row_ptr,
                                                 const int* __restrict__ sorted_src,
                                                 const float* __restrict__ eps_ptr,
                                                 uint32* __restrict__ zb32) {
    __shared__ int sbuf[4][64];
    __shared__ float mbuf[4][64];
    int lane = threadIdx.x & 63, wv = threadIdx.x >> 6;
    int node = blockIdx.x * 4 + wv;
    int start = row_ptr[node];
    int deg = row_ptr[node + 1] - start;
    float acc0 = 0.f, acc1 = 0.f;
    if (deg > 0) {
        int s_pad = sorted_src[start];
        for (int j0 = 0; j0 < deg; j0 += 64) {
            int j = j0 + lane;
            int s = s_pad;
            float m = 0.f;
            if (j < deg) { s = sorted_src[start + j]; m = 1.f; }
            sbuf[wv][lane] = s;
            mbuf[wv][lane] = m;
            __builtin_amdgcn_wave_barrier();
            int nj8 = min(64, deg - j0);
            nj8 = (nj8 + 7) & ~7;
            for (int jj = 0; jj < nj8; jj += 8) {
#pragma unroll
                for (int u = 0; u < 8; ++u) {
                    int ss = sbuf[wv][jj + u];
                    float mm = mbuf[wv][jj + u];
                    uint32 hv = ob32[(size_t)ss * 64 + lane];
                    acc0 += mm * __uint_as_float(hv << 16);
                    acc1 += mm * __uint_as_float(hv & 0xffff0000u);
                }
            }
            __builtin_amdgcn_wave_barrier();
        }
    }
    float ep = 1.f + eps_ptr[0];
    uint32 own = ob32[(size_t)node * 64 + lane];
    float z0 = ep * __uint_as_float(own << 16) + acc0;
    float z1 = ep * __uint_as_float(own & 0xffff0000u) + acc1;
    zb32[(size_t)node * 64 + lane] = (uint32)f2bf(z0) | ((uint32)f2bf(z1) << 16);
}

// ---------------- BN stats ----------------
__global__ __launch_bounds__(256) void k_bnstats(const float* __restrict__ buf,
                                                 float* __restrict__ acc) {
    __shared__ float sh[512];
    int t = threadIdx.x;
    int c = t & 127;
    float s = 0.f, s2 = 0.f;
    for (int r = blockIdx.x * 2 + (t >> 7); r < N_NODES; r += gridDim.x * 2) {
        float v = buf[(size_t)r * 128 + c];
        s += v;
        s2 += v * v;
    }
    sh[t] = s;
    sh[256 + t] = s2;
    __syncthreads();
    if (t < 128) {
        atomicAdd(&acc[c], sh[t] + sh[t + 128]);
        atomicAdd(&acc[128 + c], sh[256 + t] + sh[256 + t + 128]);
    }
}

__global__ void k_bnparams(const float* __restrict__ acc, const float* __restrict__ gamma,
                           const float* __restrict__ beta, float* __restrict__ ss) {
    int c = threadIdx.x;
    if (c < 128) {
        float mu = acc[c] * (1.f / N_NODES);
        float var = acc[128 + c] * (1.f / N_NODES) - mu * mu;
        float rs = rsqrtf(var + BN_EPS);
        float sc = rs * gamma[c];
        ss[c] = sc;
        ss[128 + c] = beta[c] - mu * sc;
    }
}

// ---------------- BN + ELU -> bf16 out ----------------
__global__ __launch_bounds__(256) void k_bn_elu_bf16(const float* __restrict__ in,
                                                     const float* __restrict__ ss,
                                                     unsigned short* __restrict__ outb) {
    size_t i = (size_t)blockIdx.x * 256 + threadIdx.x;
    if (i >= (size_t)N_NODES * 32) return;
    int c4 = (int)(i & 31) * 4;
    float4 v = *(const float4*)&in[i * 4];
    float4 sc = *(const float4*)&ss[c4];
    float4 sh = *(const float4*)&ss[128 + c4];
    float r0 = v.x * sc.x + sh.x;
    float r1 = v.y * sc.y + sh.y;
    float r2 = v.z * sc.z + sh.z;
    float r3 = v.w * sc.w + sh.w;
    r0 = r0 > 0.f ? r0 : __expf(r0) - 1.f;
    r1 = r1 > 0.f ? r1 : __expf(r1) - 1.f;
    r2 = r2 > 0.f ? r2 : __expf(r2) - 1.f;
    r3 = r3 > 0.f ? r3 : __expf(r3) - 1.f;
    ushort4 b;
    b.x = f2bf(r0); b.y = f2bf(r1); b.z = f2bf(r2); b.w = f2bf(r3);
    *(ushort4*)&outb[i * 4] = b;
}

// ---------------- BN + ELU fp32 in place ----------------
__global__ __launch_bounds__(256) void k_bn_elu(float* __restrict__ buf,
                                                const float* __restrict__ ss) {
    size_t i = (size_t)blockIdx.x * 256 + threadIdx.x;
    if (i >= (size_t)N_NODES * 32) return;
    int c4 = (int)(i & 31) * 4;
    float4 v = *(float4*)&buf[i * 4];
    float4 sc = *(const float4*)&ss[c4];
    float4 sh = *(const float4*)&ss[128 + c4];
    float r0 = v.x * sc.x + sh.x;
    float r1 = v.y * sc.y + sh.y;
    float r2 = v.z * sc.z + sh.z;
    float r3 = v.w * sc.w + sh.w;
    r0 = r0 > 0.f ? r0 : __expf(r0) - 1.f;
    r1 = r1 > 0.f ? r1 : __expf(r1) - 1.f;
    r2 = r2 > 0.f ? r2 : __expf(r2) - 1.f;
    r3 = r3 > 0.f ? r3 : __expf(r3) - 1.f;
    *(float4*)&buf[i * 4] = make_float4(r0, r1, r2, r3);
}

extern "C" void kernel_launch(void* const* d_in, const int* in_sizes, int n_in,
                              void* d_out, int out_size, void* d_ws, size_t ws_size,
                              hipStream_t stream) {
    (void)in_sizes; (void)n_in; (void)out_size; (void)ws_size;
    const float* x       = (const float*)d_in[0];
    const float* W_gat   = (const float*)d_in[1];
    const float* att_src = (const float*)d_in[2];
    const float* att_dst = (const float*)d_in[3];
    // d_in[4] bias_gat, d_in[9] lin_b: per-channel biases cancel exactly under BN -> dropped
    const float* bn1_g   = (const float*)d_in[5];
    const float* bn1_b   = (const float*)d_in[6];
    const float* eps_gin = (const float*)d_in[7];
    const float* lin_W   = (const float*)d_in[8];
    const float* bn2_g   = (const float*)d_in[10];
    const float* bn2_b   = (const float*)d_in[11];
    const int*   ei      = (const int*)d_in[12];
    float* out = (float*)d_out;

    char* w = (char*)d_ws;
    size_t o = 0;
    auto take = [&](size_t b) -> char* {
        char* p = w + o;
        o += (b + 255) & ~(size_t)255;
        return p;
    };
    unsigned short* hb   = (unsigned short*)take((size_t)N_NODES * 128 * 2);
    unsigned short* Wt1  = (unsigned short*)take((size_t)128 * IN_C * 2);
    unsigned short* Wt2  = (unsigned short*)take((size_t)128 * HID * 2);
    float* out1          = (float*)take((size_t)N_NODES * 128 * 4);
    unsigned short* o1b  = (unsigned short*)take((size_t)N_NODES * 128 * 2);
    float* a_src         = (float*)take((size_t)N_NODES * 4 * 4);
    float* a_dst         = (float*)take((size_t)N_NODES * 4 * 4);
    int*   sorted        = (int*)take((size_t)N_EDGES * 4);
    float4* wsorted      = (float4*)take((size_t)N_EDGES * 16);
    int*   row_ptr       = (int*)take((size_t)(N_NODES + 1) * 4);
    int*   counts        = (int*)take((size_t)N_NODES * 4);
    int*   cursor        = (int*)take((size_t)N_NODES * 4);
    int*   bsums         = (int*)take(4096);
    int*   boffs         = (int*)take(4096);
    float* bnacc         = (float*)take(512 * 4);
    float* ss1           = (float*)take(256 * 4);
    float* ss2           = (float*)take(256 * 4);
    unsigned short* zb = hb;  // reuse: hb dead after k_gat_agg

    const int nScanBlocks = (N_NODES + 1023) / 1024;
    const int nGemmBlocks = (N_NODES + 127) / 128;

    k_init<<<(N_NODES + 255) / 256, 256, 0, stream>>>(counts, cursor, bnacc);
    k_transpose_bf16<<<(IN_C * 128 + 255) / 256, 256, 0, stream>>>(W_gat, Wt1, IN_C);
    k_transpose_bf16<<<(HID * 128 + 255) / 256, 256, 0, stream>>>(lin_W, Wt2, HID);
    k_gemm<true, false><<<nGemmBlocks, 256, 0, stream>>>(x, Wt1, hb, IN_C);
    k_att<<<N_NODES / 2, 256, 0, stream>>>(hb, att_src, att_dst, a_src, a_dst);
    k_hist<<<(N_EDGES + 255) / 256, 256, 0, stream>>>(ei, counts);
    k_scan_a<<<nScanBlocks, 256, 0, stream>>>(counts, row_ptr, bsums);
    k_scan_b<<<1, 64, 0, stream>>>(bsums, boffs, row_ptr, nScanBlocks);
    k_scan_c<<<nScanBlocks, 256, 0, stream>>>(row_ptr, boffs);
    k_scatter_w<<<(N_EDGES + 255) / 256, 256, 0, stream>>>(ei, row_ptr, cursor, a_src,
                                                           a_dst, sorted, wsorted);
    k_gat_agg<<<N_NODES / 4, 256, 0, stream>>>((const uint32*)hb, row_ptr, sorted,
                                               wsorted, out1);
    k_bnstats<<<512, 256, 0, stream>>>(out1, bnacc);
    k_bnparams<<<1, 128, 0, stream>>>(bnacc, bn1_g, bn1_b, ss1);
    k_bn_elu_bf16<<<N_NODES * 32 / 256, 256, 0, stream>>>(out1, ss1, o1b);
    k_gin_agg<<<N_NODES / 4, 256, 0, stream>>>((const uint32*)o1b, row_ptr, sorted,
                                               eps_gin, (uint32*)zb);
    k_gemm<false, true><<<nGemmBlocks, 256, 0, stream>>>(zb, Wt2, out, HID);
    k_bnstats<<<512, 256, 0, stream>>>(out, bnacc + 256);
    k_bnparams<<<1, 128, 0, stream>>>(bnacc + 256, bn2_g, bn2_b, ss2);
    k_bn_elu<<<N_NODES * 32 / 256, 256, 0, stream>>>(out, ss2);
}

// Round 3
// 662.292 us; speedup vs baseline: 1.4081x; 1.0062x over previous
//
#include <hip/hip_runtime.h>

#define N_NODES 100000
#define N_EDGES 1600000
#define IN_C 256
#define HID 128
#define NEG_SLOPE 0.2f
#define BN_EPS 1e-5f

typedef unsigned int uint32;
typedef __attribute__((ext_vector_type(8))) short bf16x8;
typedef __attribute__((ext_vector_type(4))) float f32x4;

__device__ __forceinline__ float lrelu(float x) { return x > 0.f ? x : NEG_SLOPE * x; }

__device__ __forceinline__ unsigned short f2bf(float f) {
    uint32 u = __float_as_uint(f);
    u += 0x7fffu + ((u >> 16) & 1u);
    return (unsigned short)(u >> 16);
}
__device__ __forceinline__ float bf2f(unsigned short h) {
    return __uint_as_float(((uint32)h) << 16);
}
__device__ __forceinline__ float bflo(uint32 v) { return __uint_as_float(v << 16); }
__device__ __forceinline__ float bfhi(uint32 v) { return __uint_as_float(v & 0xffff0000u); }
__device__ __forceinline__ uint32 packbf(float a, float b) {
    return (uint32)f2bf(a) | ((uint32)f2bf(b) << 16);
}

// ---------------- init ----------------
__global__ void k_init(int* __restrict__ counts, int* __restrict__ cursor,
                       float* __restrict__ bnacc) {
    int i = blockIdx.x * 256 + threadIdx.x;
    if (i < N_NODES) { counts[i] = 0; cursor[i] = 0; }
    if (i < 512) bnacc[i] = 0.f;
}

// ---------------- transpose W [K][128] fp32 -> Wt [128][K] bf16 ----------------
__global__ void k_transpose_bf16(const float* __restrict__ W, unsigned short* __restrict__ Wt,
                                 int K) {
    int idx = blockIdx.x * 256 + threadIdx.x;
    if (idx >= K * 128) return;
    int k = idx >> 7, n = idx & 127;
    Wt[n * K + k] = f2bf(W[idx]);
}

// ---------------- MFMA GEMM: Out[M,128] = A[M,K] @ Wt[n][k] ----------------
template <bool AF32, bool OUTF32>
__global__ __launch_bounds__(256) void k_gemm(const void* __restrict__ Av,
                                              const unsigned short* __restrict__ Wt,
                                              void* __restrict__ Out, int K) {
    __shared__ unsigned short As[128 * 72];
    __shared__ unsigned short Bs[128 * 72];
    const int t = threadIdx.x;
    const int n0 = blockIdx.x * 128;
    const int wv = t >> 6, lane = t & 63;
    const int wy = wv >> 1, wx = wv & 1;
    const int lm = lane & 15, lg = lane >> 4;

    f32x4 acc[4][4];
#pragma unroll
    for (int i = 0; i < 4; ++i)
#pragma unroll
        for (int j = 0; j < 4; ++j) acc[i][j] = (f32x4){0.f, 0.f, 0.f, 0.f};

    for (int kc = 0; kc < K; kc += 64) {
        if (AF32) {
            const float* A = (const float*)Av;
#pragma unroll
            for (int p = 0; p < 8; ++p) {
                int idx = p * 256 + t;
                int row = idx >> 4, c4 = idx & 15;
                int gn = n0 + row;
                float4 v = make_float4(0.f, 0.f, 0.f, 0.f);
                if (gn < N_NODES) v = *(const float4*)&A[(size_t)gn * K + kc + c4 * 4];
                ushort4 b;
                b.x = f2bf(v.x); b.y = f2bf(v.y); b.z = f2bf(v.z); b.w = f2bf(v.w);
                *(ushort4*)&As[row * 72 + c4 * 4] = b;
            }
        } else {
            const unsigned short* A = (const unsigned short*)Av;
#pragma unroll
            for (int p = 0; p < 4; ++p) {
                int idx = p * 256 + t;
                int row = idx >> 3, c = idx & 7;
                int gn = n0 + row;
                uint4 v = make_uint4(0, 0, 0, 0);
                if (gn < N_NODES) v = *(const uint4*)&A[(size_t)gn * K + kc + c * 8];
                *(uint4*)&As[row * 72 + c * 8] = v;
            }
        }
#pragma unroll
        for (int p = 0; p < 4; ++p) {
            int idx = p * 256 + t;
            int n = idx >> 3, c = idx & 7;
            uint4 v = *(const uint4*)&Wt[(size_t)n * K + kc + c * 8];
            *(uint4*)&Bs[n * 72 + c * 8] = v;
        }
        __syncthreads();
#pragma unroll
        for (int ks = 0; ks < 2; ++ks) {
            bf16x8 af[4], bfr[4];
#pragma unroll
            for (int i = 0; i < 4; ++i)
                af[i] = *(const bf16x8*)&As[(wy * 64 + i * 16 + lm) * 72 + ks * 32 + lg * 8];
#pragma unroll
            for (int j = 0; j < 4; ++j)
                bfr[j] = *(const bf16x8*)&Bs[(wx * 64 + j * 16 + lm) * 72 + ks * 32 + lg * 8];
#pragma unroll
            for (int i = 0; i < 4; ++i)
#pragma unroll
                for (int j = 0; j < 4; ++j)
                    acc[i][j] = __builtin_amdgcn_mfma_f32_16x16x32_bf16(af[i], bfr[j],
                                                                        acc[i][j], 0, 0, 0);
        }
        __syncthreads();
    }
#pragma unroll
    for (int i = 0; i < 4; ++i) {
#pragma unroll
        for (int r = 0; r < 4; ++r) {
            int row = n0 + wy * 64 + i * 16 + lg * 4 + r;
            if (row < N_NODES) {
#pragma unroll
                for (int j = 0; j < 4; ++j) {
                    int col = wx * 64 + j * 16 + lm;
                    float v = acc[i][j][r];
                    if (OUTF32) ((float*)Out)[(size_t)row * 128 + col] = v;
                    else ((unsigned short*)Out)[(size_t)row * 128 + col] = f2bf(v);
                }
            }
        }
    }
}

// ---------------- attention coefficients ----------------
__global__ __launch_bounds__(256) void k_att(const unsigned short* __restrict__ hb,
                                             const float* __restrict__ att_s,
                                             const float* __restrict__ att_d,
                                             float* __restrict__ a_src,
                                             float* __restrict__ a_dst) {
    int node = blockIdx.x * 2 + (threadIdx.x >> 7);
    int c = threadIdx.x & 127;
    float hv = bf2f(hb[(size_t)node * 128 + c]);
    float ps = hv * att_s[c];
    float pd = hv * att_d[c];
#pragma unroll
    for (int m = 1; m < 32; m <<= 1) {
        ps += __shfl_xor(ps, m);
        pd += __shfl_xor(pd, m);
    }
    if ((c & 31) == 0) {
        int head = c >> 5;
        a_src[node * 4 + head] = ps;
        a_dst[node * 4 + head] = pd;
    }
}

// ---------------- CSR build ----------------
__global__ void k_hist(const int* __restrict__ ei, int* __restrict__ counts) {
    int e = blockIdx.x * 256 + threadIdx.x;
    if (e < N_EDGES) atomicAdd(&counts[ei[N_EDGES + e]], 1);
}

__global__ __launch_bounds__(256) void k_scan_a(const int* __restrict__ counts,
                                                int* __restrict__ row_ptr,
                                                int* __restrict__ bsums) {
    __shared__ int sh[256];
    int t = threadIdx.x;
    int base = blockIdx.x * 1024 + t * 4;
    int4 v = make_int4(0, 0, 0, 0);
    if (base + 3 < N_NODES) v = *(const int4*)&counts[base];
    else {
        if (base + 0 < N_NODES) v.x = counts[base + 0];
        if (base + 1 < N_NODES) v.y = counts[base + 1];
        if (base + 2 < N_NODES) v.z = counts[base + 2];
        if (base + 3 < N_NODES) v.w = counts[base + 3];
    }
    int tsum = v.x + v.y + v.z + v.w;
    sh[t] = tsum;
    __syncthreads();
    int val = tsum;
    for (int off = 1; off < 256; off <<= 1) {
        int other = (t >= off) ? sh[t - off] : 0;
        __syncthreads();
        val += other;
        sh[t] = val;
        __syncthreads();
    }
    int run = val - tsum;
    if (base + 0 < N_NODES) row_ptr[base + 0] = run; run += v.x;
    if (base + 1 < N_NODES) row_ptr[base + 1] = run; run += v.y;
    if (base + 2 < N_NODES) row_ptr[base + 2] = run; run += v.z;
    if (base + 3 < N_NODES) row_ptr[base + 3] = run;
    if (t == 255) bsums[blockIdx.x] = val;
}

__global__ void k_scan_b(const int* __restrict__ bsums, int* __restrict__ boffs,
                         int* __restrict__ row_ptr, int nb) {
    int lane = threadIdx.x;
    int o0 = (lane < nb) ? bsums[lane] : 0;
    int o1 = (64 + lane < nb) ? bsums[64 + lane] : 0;
    int v0 = o0, v1 = o1;
#pragma unroll
    for (int off = 1; off < 64; off <<= 1) {
        int t0 = __shfl_up(v0, off);
        int t1 = __shfl_up(v1, off);
        if (lane >= off) { v0 += t0; v1 += t1; }
    }
    int tot0 = __shfl(v0, 63);
    if (lane < nb) boffs[lane] = v0 - o0;
    if (64 + lane < nb) boffs[64 + lane] = tot0 + v1 - o1;
    if (lane == 63) row_ptr[N_NODES] = tot0 + v1;
}

__global__ void k_scan_c(int* __restrict__ row_ptr, const int* __restrict__ boffs) {
    int base = blockIdx.x * 1024 + threadIdx.x * 4;
    int off = boffs[blockIdx.x];
#pragma unroll
    for (int i = 0; i < 4; ++i) {
        int idx = base + i;
        if (idx < N_NODES) row_ptr[idx] += off;
    }
}

// ---------------- scatter: 4B/edge only ----------------
__global__ void k_scatter(const int* __restrict__ ei, const int* __restrict__ row_ptr,
                          int* __restrict__ cursor, int* __restrict__ sorted_src) {
    int e = blockIdx.x * 256 + threadIdx.x;
    if (e >= N_EDGES) return;
    int s = ei[e], d = ei[N_EDGES + e];
    int pos = row_ptr[d] + atomicAdd(&cursor[d], 1);
    __builtin_nontemporal_store(s, &sorted_src[pos]);
}

// ---------------- GAT aggregate: single pass, deferred normalization ----------------
__global__ __launch_bounds__(256) void k_gat_agg(const uint32* __restrict__ hb32,
                                                 const float* __restrict__ a_src,
                                                 const float* __restrict__ a_dst,
                                                 const int* __restrict__ row_ptr,
                                                 const int* __restrict__ sorted_src,
                                                 uint32* __restrict__ out1b) {
    __shared__ int sbuf[4][64];
    __shared__ float wbuf[4][64][4];
    int lane = threadIdx.x & 63, wv = threadIdx.x >> 6;
    int node = blockIdx.x * 4 + wv;
    int start = row_ptr[node];
    int deg = row_ptr[node + 1] - start;
    if (deg == 0) {
        out1b[(size_t)node * 64 + lane] = 0u;
        return;
    }
    int head = lane >> 4;
    float4 ad = *(const float4*)&a_dst[node * 4];
    float acc0 = 0.f, acc1 = 0.f, den = 0.f;
    for (int j0 = 0; j0 < deg; j0 += 64) {
        int j = j0 + lane;
        int s = 0;
        float4 w = make_float4(0.f, 0.f, 0.f, 0.f);
        if (j < deg) {
            s = sorted_src[start + j];
            float4 as = *(const float4*)&a_src[s * 4];
            w.x = __expf(lrelu(as.x + ad.x));
            w.y = __expf(lrelu(as.y + ad.y));
            w.z = __expf(lrelu(as.z + ad.z));
            w.w = __expf(lrelu(as.w + ad.w));
        }
        sbuf[wv][lane] = s;
        *(float4*)&wbuf[wv][lane][0] = w;
        __builtin_amdgcn_wave_barrier();
        int nj8 = (min(64, deg - j0) + 7) & ~7;
        for (int jj = 0; jj < nj8; jj += 8) {
#pragma unroll
            for (int u = 0; u < 8; ++u) {
                int ss = sbuf[wv][jj + u];
                float wh = wbuf[wv][jj + u][head];   // padded lanes have w=0
                den += wh;
                uint32 hv = hb32[(size_t)ss * 64 + lane];
                acc0 += wh * bflo(hv);
                acc1 += wh * bfhi(hv);
            }
        }
        __builtin_amdgcn_wave_barrier();
    }
    float rden = 1.f / den;
    out1b[(size_t)node * 64 + lane] = packbf(acc0 * rden, acc1 * rden);
}

// ---------------- GIN aggregate ----------------
__global__ __launch_bounds__(256) void k_gin_agg(const uint32* __restrict__ ob32,
                                                 const int* __restrict__ row_ptr,
                                                 const int* __restrict__ sorted_src,
                                                 const float* __restrict__ eps_ptr,
                                                 uint32* __restrict__ zb32) {
    __shared__ int sbuf[4][64];
    __shared__ float mbuf[4][64];
    int lane = threadIdx.x & 63, wv = threadIdx.x >> 6;
    int node = blockIdx.x * 4 + wv;
    int start = row_ptr[node];
    int deg = row_ptr[node + 1] - start;
    float acc0 = 0.f, acc1 = 0.f;
    if (deg > 0) {
        for (int j0 = 0; j0 < deg; j0 += 64) {
            int j = j0 + lane;
            int s = 0;
            float m = 0.f;
            if (j < deg) { s = sorted_src[start + j]; m = 1.f; }
            sbuf[wv][lane] = s;
            mbuf[wv][lane] = m;
            __builtin_amdgcn_wave_barrier();
            int nj8 = (min(64, deg - j0) + 7) & ~7;
            for (int jj = 0; jj < nj8; jj += 8) {
#pragma unroll
                for (int u = 0; u < 8; ++u) {
                    int ss = sbuf[wv][jj + u];
                    float mm = mbuf[wv][jj + u];
                    uint32 hv = ob32[(size_t)ss * 64 + lane];
                    acc0 += mm * bflo(hv);
                    acc1 += mm * bfhi(hv);
                }
            }
            __builtin_amdgcn_wave_barrier();
        }
    }
    float ep = 1.f + eps_ptr[0];
    uint32 own = ob32[(size_t)node * 64 + lane];
    zb32[(size_t)node * 64 + lane] = packbf(ep * bflo(own) + acc0, ep * bfhi(own) + acc1);
}

// ---------------- BN stats (bf16 input) ----------------
__global__ __launch_bounds__(256) void k_bnstats_bf16(const uint32* __restrict__ buf,
                                                      float* __restrict__ acc) {
    __shared__ float sh[4][64][4];
    int lane = threadIdx.x & 63, grp = threadIdx.x >> 6;
    float s0 = 0.f, s1 = 0.f, q0 = 0.f, q1 = 0.f;
    for (int r = blockIdx.x * 4 + grp; r < N_NODES; r += gridDim.x * 4) {
        uint32 v = buf[(size_t)r * 64 + lane];
        float v0 = bflo(v), v1 = bfhi(v);
        s0 += v0; s1 += v1; q0 += v0 * v0; q1 += v1 * v1;
    }
    sh[grp][lane][0] = s0; sh[grp][lane][1] = s1;
    sh[grp][lane][2] = q0; sh[grp][lane][3] = q1;
    __syncthreads();
    if (grp == 0) {
#pragma unroll
        for (int g = 1; g < 4; ++g) {
            s0 += sh[g][lane][0]; s1 += sh[g][lane][1];
            q0 += sh[g][lane][2]; q1 += sh[g][lane][3];
        }
        int c0 = lane * 2;
        atomicAdd(&acc[c0], s0);
        atomicAdd(&acc[c0 + 1], s1);
        atomicAdd(&acc[128 + c0], q0);
        atomicAdd(&acc[128 + c0 + 1], q1);
    }
}

// ---------------- BN stats (fp32 input) ----------------
__global__ __launch_bounds__(256) void k_bnstats(const float* __restrict__ buf,
                                                 float* __restrict__ acc) {
    __shared__ float sh[512];
    int t = threadIdx.x;
    int c = t & 127;
    float s = 0.f, s2 = 0.f;
    for (int r = blockIdx.x * 2 + (t >> 7); r < N_NODES; r += gridDim.x * 2) {
        float v = buf[(size_t)r * 128 + c];
        s += v;
        s2 += v * v;
    }
    sh[t] = s;
    sh[256 + t] = s2;
    __syncthreads();
    if (t < 128) {
        atomicAdd(&acc[c], sh[t] + sh[t + 128]);
        atomicAdd(&acc[128 + c], sh[256 + t] + sh[256 + t + 128]);
    }
}

__global__ void k_bnparams(const float* __restrict__ acc, const float* __restrict__ gamma,
                           const float* __restrict__ beta, float* __restrict__ ss) {
    int c = threadIdx.x;
    if (c < 128) {
        float mu = acc[c] * (1.f / N_NODES);
        float var = acc[128 + c] * (1.f / N_NODES) - mu * mu;
        float rs = rsqrtf(var + BN_EPS);
        float sc = rs * gamma[c];
        ss[c] = sc;
        ss[128 + c] = beta[c] - mu * sc;
    }
}

// ---------------- BN + ELU in-place on bf16 buffer ----------------
__global__ __launch_bounds__(256) void k_bn_elu_b16(uint32* __restrict__ buf,
                                                    const float* __restrict__ ss) {
    size_t i = (size_t)blockIdx.x * 256 + threadIdx.x;  // uint32 index (2 ch)
    if (i >= (size_t)N_NODES * 64) return;
    int c0 = (int)(i & 63) * 2;
    uint32 v = buf[i];
    float r0 = bflo(v) * ss[c0] + ss[128 + c0];
    float r1 = bfhi(v) * ss[c0 + 1] + ss[128 + c0 + 1];
    r0 = r0 > 0.f ? r0 : __expf(r0) - 1.f;
    r1 = r1 > 0.f ? r1 : __expf(r1) - 1.f;
    buf[i] = packbf(r0, r1);
}

// ---------------- BN + ELU fp32 in place ----------------
__global__ __launch_bounds__(256) void k_bn_elu(float* __restrict__ buf,
                                                const float* __restrict__ ss) {
    size_t i = (size_t)blockIdx.x * 256 + threadIdx.x;
    if (i >= (size_t)N_NODES * 32) return;
    int c4 = (int)(i & 31) * 4;
    float4 v = *(float4*)&buf[i * 4];
    float4 sc = *(const float4*)&ss[c4];
    float4 sh = *(const float4*)&ss[128 + c4];
    float r0 = v.x * sc.x + sh.x;
    float r1 = v.y * sc.y + sh.y;
    float r2 = v.z * sc.z + sh.z;
    float r3 = v.w * sc.w + sh.w;
    r0 = r0 > 0.f ? r0 : __expf(r0) - 1.f;
    r1 = r1 > 0.f ? r1 : __expf(r1) - 1.f;
    r2 = r2 > 0.f ? r2 : __expf(r2) - 1.f;
    r3 = r3 > 0.f ? r3 : __expf(r3) - 1.f;
    *(float4*)&buf[i * 4] = make_float4(r0, r1, r2, r3);
}

extern "C" void kernel_launch(void* const* d_in, const int* in_sizes, int n_in,
                              void* d_out, int out_size, void* d_ws, size_t ws_size,
                              hipStream_t stream) {
    (void)in_sizes; (void)n_in; (void)out_size; (void)ws_size;
    const float* x       = (const float*)d_in[0];
    const float* W_gat   = (const float*)d_in[1];
    const float* att_src = (const float*)d_in[2];
    const float* att_dst = (const float*)d_in[3];
    // bias_gat / lin_b cancel exactly under batch-norm -> dropped
    const float* bn1_g   = (const float*)d_in[5];
    const float* bn1_b   = (const float*)d_in[6];
    const float* eps_gin = (const float*)d_in[7];
    const float* lin_W   = (const float*)d_in[8];
    const float* bn2_g   = (const float*)d_in[10];
    const float* bn2_b   = (const float*)d_in[11];
    const int*   ei      = (const int*)d_in[12];
    float* out = (float*)d_out;

    char* w = (char*)d_ws;
    size_t o = 0;
    auto take = [&](size_t b) -> char* {
        char* p = w + o;
        o += (b + 255) & ~(size_t)255;
        return p;
    };
    unsigned short* hb   = (unsigned short*)take((size_t)N_NODES * 128 * 2);
    unsigned short* Wt1  = (unsigned short*)take((size_t)128 * IN_C * 2);
    unsigned short* Wt2  = (unsigned short*)take((size_t)128 * HID * 2);
    uint32* o1b          = (uint32*)take((size_t)N_NODES * 64 * 4);
    float* a_src         = (float*)take((size_t)N_NODES * 4 * 4);
    float* a_dst         = (float*)take((size_t)N_NODES * 4 * 4);
    int*   sorted        = (int*)take((size_t)N_EDGES * 4);
    int*   row_ptr       = (int*)take((size_t)(N_NODES + 1) * 4);
    int*   counts        = (int*)take((size_t)N_NODES * 4);
    int*   cursor        = (int*)take((size_t)N_NODES * 4);
    int*   bsums         = (int*)take(4096);
    int*   boffs         = (int*)take(4096);
    float* bnacc         = (float*)take(512 * 4);
    float* ss1           = (float*)take(256 * 4);
    float* ss2           = (float*)take(256 * 4);
    uint32* zb = (uint32*)hb;  // reuse: hb dead after k_gat_agg

    const int nScanBlocks = (N_NODES + 1023) / 1024;
    const int nGemmBlocks = (N_NODES + 127) / 128;

    k_init<<<(N_NODES + 255) / 256, 256, 0, stream>>>(counts, cursor, bnacc);
    k_transpose_bf16<<<(IN_C * 128 + 255) / 256, 256, 0, stream>>>(W_gat, Wt1, IN_C);
    k_transpose_bf16<<<(HID * 128 + 255) / 256, 256, 0, stream>>>(lin_W, Wt2, HID);
    k_gemm<true, false><<<nGemmBlocks, 256, 0, stream>>>(x, Wt1, hb, IN_C);
    k_att<<<N_NODES / 2, 256, 0, stream>>>(hb, att_src, att_dst, a_src, a_dst);
    k_hist<<<(N_EDGES + 255) / 256, 256, 0, stream>>>(ei, counts);
    k_scan_a<<<nScanBlocks, 256, 0, stream>>>(counts, row_ptr, bsums);
    k_scan_b<<<1, 64, 0, stream>>>(bsums, boffs, row_ptr, nScanBlocks);
    k_scan_c<<<nScanBlocks, 256, 0, stream>>>(row_ptr, boffs);
    k_scatter<<<(N_EDGES + 255) / 256, 256, 0, stream>>>(ei, row_ptr, cursor, sorted);
    k_gat_agg<<<N_NODES / 4, 256, 0, stream>>>((const uint32*)hb, a_src, a_dst, row_ptr,
                                               sorted, o1b);
    k_bnstats_bf16<<<512, 256, 0, stream>>>(o1b, bnacc);
    k_bnparams<<<1, 128, 0, stream>>>(bnacc, bn1_g, bn1_b, ss1);
    k_bn_elu_b16<<<(N_NODES * 64 + 255) / 256, 256, 0, stream>>>(o1b, ss1);
    k_gin_agg<<<N_NODES / 4, 256, 0, stream>>>(o1b, row_ptr, sorted, eps_gin, zb);
    k_gemm<false, true><<<nGemmBlocks, 256, 0, stream>>>(zb, Wt2, out, HID);
    k_bnstats<<<512, 256, 0, stream>>>(out, bnacc + 256);
    k_bnparams<<<1, 128, 0, stream>>>(bnacc + 256, bn2_g, bn2_b, ss2);
    k_bn_elu<<<N_NODES * 32 / 256, 256, 0, stream>>>(out, ss2);
}

// Round 4
// 635.230 us; speedup vs baseline: 1.4681x; 1.0426x over previous
//
#include <hip/hip_runtime.h>

#define N_NODES 100000
#define N_EDGES 1600000
#define IN_C 256
#define HID 128
#define NEG_SLOPE 0.2f
#define BN_EPS 1e-5f
#define N_TEAMS 8
#define TEAM_DST (N_NODES / N_TEAMS)  // 12500, exact

typedef unsigned int uint32;
typedef __attribute__((ext_vector_type(8))) short bf16x8;
typedef __attribute__((ext_vector_type(4))) float f32x4;

__device__ __forceinline__ float lrelu(float x) { return x > 0.f ? x : NEG_SLOPE * x; }

__device__ __forceinline__ unsigned short f2bf(float f) {
    uint32 u = __float_as_uint(f);
    u += 0x7fffu + ((u >> 16) & 1u);
    return (unsigned short)(u >> 16);
}
__device__ __forceinline__ float bf2f(unsigned short h) {
    return __uint_as_float(((uint32)h) << 16);
}
__device__ __forceinline__ float bflo(uint32 v) { return __uint_as_float(v << 16); }
__device__ __forceinline__ float bfhi(uint32 v) { return __uint_as_float(v & 0xffff0000u); }
__device__ __forceinline__ uint32 packbf(float a, float b) {
    return (uint32)f2bf(a) | ((uint32)f2bf(b) << 16);
}

// ---------------- init ----------------
__global__ void k_init(int* __restrict__ counts, int* __restrict__ cursor,
                       float* __restrict__ bnacc) {
    int i = blockIdx.x * 256 + threadIdx.x;
    if (i < N_NODES) { counts[i] = 0; cursor[i] = 0; }
    if (i < 512) bnacc[i] = 0.f;
}

// ---------------- transpose W [K][128] fp32 -> Wt [128][K] bf16 ----------------
__global__ void k_transpose_bf16(const float* __restrict__ W, unsigned short* __restrict__ Wt,
                                 int K) {
    int idx = blockIdx.x * 256 + threadIdx.x;
    if (idx >= K * 128) return;
    int k = idx >> 7, n = idx & 127;
    Wt[n * K + k] = f2bf(W[idx]);
}

// ---------------- MFMA GEMM: Out[M,128] = A[M,K] @ Wt[n][k] ----------------
template <bool AF32, bool OUTF32>
__global__ __launch_bounds__(256) void k_gemm(const void* __restrict__ Av,
                                              const unsigned short* __restrict__ Wt,
                                              void* __restrict__ Out, int K) {
    __shared__ unsigned short As[128 * 72];
    __shared__ unsigned short Bs[128 * 72];
    const int t = threadIdx.x;
    const int n0 = blockIdx.x * 128;
    const int wv = t >> 6, lane = t & 63;
    const int wy = wv >> 1, wx = wv & 1;
    const int lm = lane & 15, lg = lane >> 4;

    f32x4 acc[4][4];
#pragma unroll
    for (int i = 0; i < 4; ++i)
#pragma unroll
        for (int j = 0; j < 4; ++j) acc[i][j] = (f32x4){0.f, 0.f, 0.f, 0.f};

    for (int kc = 0; kc < K; kc += 64) {
        if (AF32) {
            const float* A = (const float*)Av;
#pragma unroll
            for (int p = 0; p < 8; ++p) {
                int idx = p * 256 + t;
                int row = idx >> 4, c4 = idx & 15;
                int gn = n0 + row;
                float4 v = make_float4(0.f, 0.f, 0.f, 0.f);
                if (gn < N_NODES) v = *(const float4*)&A[(size_t)gn * K + kc + c4 * 4];
                ushort4 b;
                b.x = f2bf(v.x); b.y = f2bf(v.y); b.z = f2bf(v.z); b.w = f2bf(v.w);
                *(ushort4*)&As[row * 72 + c4 * 4] = b;
            }
        } else {
            const unsigned short* A = (const unsigned short*)Av;
#pragma unroll
            for (int p = 0; p < 4; ++p) {
                int idx = p * 256 + t;
                int row = idx >> 3, c = idx & 7;
                int gn = n0 + row;
                uint4 v = make_uint4(0, 0, 0, 0);
                if (gn < N_NODES) v = *(const uint4*)&A[(size_t)gn * K + kc + c * 8];
                *(uint4*)&As[row * 72 + c * 8] = v;
            }
        }
#pragma unroll
        for (int p = 0; p < 4; ++p) {
            int idx = p * 256 + t;
            int n = idx >> 3, c = idx & 7;
            uint4 v = *(const uint4*)&Wt[(size_t)n * K + kc + c * 8];
            *(uint4*)&Bs[n * 72 + c * 8] = v;
        }
        __syncthreads();
#pragma unroll
        for (int ks = 0; ks < 2; ++ks) {
            bf16x8 af[4], bfr[4];
#pragma unroll
            for (int i = 0; i < 4; ++i)
                af[i] = *(const bf16x8*)&As[(wy * 64 + i * 16 + lm) * 72 + ks * 32 + lg * 8];
#pragma unroll
            for (int j = 0; j < 4; ++j)
                bfr[j] = *(const bf16x8*)&Bs[(wx * 64 + j * 16 + lm) * 72 + ks * 32 + lg * 8];
#pragma unroll
            for (int i = 0; i < 4; ++i)
#pragma unroll
                for (int j = 0; j < 4; ++j)
                    acc[i][j] = __builtin_amdgcn_mfma_f32_16x16x32_bf16(af[i], bfr[j],
                                                                        acc[i][j], 0, 0, 0);
        }
        __syncthreads();
    }
#pragma unroll
    for (int i = 0; i < 4; ++i) {
#pragma unroll
        for (int r = 0; r < 4; ++r) {
            int row = n0 + wy * 64 + i * 16 + lg * 4 + r;
            if (row < N_NODES) {
#pragma unroll
                for (int j = 0; j < 4; ++j) {
                    int col = wx * 64 + j * 16 + lm;
                    float v = acc[i][j][r];
                    if (OUTF32) ((float*)Out)[(size_t)row * 128 + col] = v;
                    else ((unsigned short*)Out)[(size_t)row * 128 + col] = f2bf(v);
                }
            }
        }
    }
}

// ---------------- attention coefficients ----------------
__global__ __launch_bounds__(256) void k_att(const unsigned short* __restrict__ hb,
                                             const float* __restrict__ att_s,
                                             const float* __restrict__ att_d,
                                             float* __restrict__ a_src,
                                             float* __restrict__ a_dst) {
    int node = blockIdx.x * 2 + (threadIdx.x >> 7);
    int c = threadIdx.x & 127;
    float hv = bf2f(hb[(size_t)node * 128 + c]);
    float ps = hv * att_s[c];
    float pd = hv * att_d[c];
#pragma unroll
    for (int m = 1; m < 32; m <<= 1) {
        ps += __shfl_xor(ps, m);
        pd += __shfl_xor(pd, m);
    }
    if ((c & 31) == 0) {
        int head = c >> 5;
        a_src[node * 4 + head] = ps;
        a_dst[node * 4 + head] = pd;
    }
}

// ---------------- CSR build ----------------
__global__ void k_hist(const int* __restrict__ ei, int* __restrict__ counts) {
    int e = blockIdx.x * 256 + threadIdx.x;
    if (e < N_EDGES) atomicAdd(&counts[ei[N_EDGES + e]], 1);
}

__global__ __launch_bounds__(256) void k_scan_a(const int* __restrict__ counts,
                                                int* __restrict__ row_ptr,
                                                int* __restrict__ bsums) {
    __shared__ int sh[256];
    int t = threadIdx.x;
    int base = blockIdx.x * 1024 + t * 4;
    int4 v = make_int4(0, 0, 0, 0);
    if (base + 3 < N_NODES) v = *(const int4*)&counts[base];
    else {
        if (base + 0 < N_NODES) v.x = counts[base + 0];
        if (base + 1 < N_NODES) v.y = counts[base + 1];
        if (base + 2 < N_NODES) v.z = counts[base + 2];
        if (base + 3 < N_NODES) v.w = counts[base + 3];
    }
    int tsum = v.x + v.y + v.z + v.w;
    sh[t] = tsum;
    __syncthreads();
    int val = tsum;
    for (int off = 1; off < 256; off <<= 1) {
        int other = (t >= off) ? sh[t - off] : 0;
        __syncthreads();
        val += other;
        sh[t] = val;
        __syncthreads();
    }
    int run = val - tsum;
    if (base + 0 < N_NODES) row_ptr[base + 0] = run; run += v.x;
    if (base + 1 < N_NODES) row_ptr[base + 1] = run; run += v.y;
    if (base + 2 < N_NODES) row_ptr[base + 2] = run; run += v.z;
    if (base + 3 < N_NODES) row_ptr[base + 3] = run;
    if (t == 255) bsums[blockIdx.x] = val;
}

__global__ void k_scan_b(const int* __restrict__ bsums, int* __restrict__ boffs,
                         int* __restrict__ row_ptr, int nb) {
    int lane = threadIdx.x;
    int o0 = (lane < nb) ? bsums[lane] : 0;
    int o1 = (64 + lane < nb) ? bsums[64 + lane] : 0;
    int v0 = o0, v1 = o1;
#pragma unroll
    for (int off = 1; off < 64; off <<= 1) {
        int t0 = __shfl_up(v0, off);
        int t1 = __shfl_up(v1, off);
        if (lane >= off) { v0 += t0; v1 += t1; }
    }
    int tot0 = __shfl(v0, 63);
    if (lane < nb) boffs[lane] = v0 - o0;
    if (64 + lane < nb) boffs[64 + lane] = tot0 + v1 - o1;
    if (lane == 63) row_ptr[N_NODES] = tot0 + v1;
}

__global__ void k_scan_c(int* __restrict__ row_ptr, const int* __restrict__ boffs) {
    int base = blockIdx.x * 1024 + threadIdx.x * 4;
    int off = boffs[blockIdx.x];
#pragma unroll
    for (int i = 0; i < 4; ++i) {
        int idx = base + i;
        if (idx < N_NODES) row_ptr[idx] += off;
    }
}

// ---------------- scatter: XCD-team partitioned ----------------
// team = blockIdx&7 maps to one XCD under round-robin dispatch (perf heuristic
// only: each team's writes land in the exclusive contiguous region
// [row_ptr[dlo], row_ptr[dhi]) regardless of where blocks actually run, so
// correctness never depends on the mapping). Each team sweeps the full edge
// list (LLC-resident, 12.8 MB) and keeps only its dst range -> write lines
// stay in one XCD's L2, written back once instead of once per 4B store.
__global__ __launch_bounds__(256) void k_scatter(const int* __restrict__ ei,
                                                 const int* __restrict__ row_ptr,
                                                 int* __restrict__ cursor,
                                                 int* __restrict__ sorted_src) {
    const int team = blockIdx.x & 7;
    const int sub = blockIdx.x >> 3;
    const int nsub = gridDim.x >> 3;
    const int dlo = team * TEAM_DST;
    const int dhi = dlo + TEAM_DST;
    for (int e = sub * 256 + threadIdx.x; e < N_EDGES; e += nsub * 256) {
        int d = ei[N_EDGES + e];
        if (d >= dlo && d < dhi) {
            int s = ei[e];
            int pos = row_ptr[d] + atomicAdd(&cursor[d], 1);
            sorted_src[pos] = s;
        }
    }
}

// ---------------- GAT aggregate: single pass, deferred normalization ----------------
__global__ __launch_bounds__(256) void k_gat_agg(const uint32* __restrict__ hb32,
                                                 const float* __restrict__ a_src,
                                                 const float* __restrict__ a_dst,
                                                 const int* __restrict__ row_ptr,
                                                 const int* __restrict__ sorted_src,
                                                 uint32* __restrict__ out1b) {
    __shared__ int sbuf[4][64];
    __shared__ float wbuf[4][64][4];
    int lane = threadIdx.x & 63, wv = threadIdx.x >> 6;
    int node = blockIdx.x * 4 + wv;
    int start = row_ptr[node];
    int deg = row_ptr[node + 1] - start;
    if (deg == 0) {
        out1b[(size_t)node * 64 + lane] = 0u;
        return;
    }
    int head = lane >> 4;
    float4 ad = *(const float4*)&a_dst[node * 4];
    float acc0 = 0.f, acc1 = 0.f, den = 0.f;
    for (int j0 = 0; j0 < deg; j0 += 64) {
        int j = j0 + lane;
        int s = 0;
        float4 w = make_float4(0.f, 0.f, 0.f, 0.f);
        if (j < deg) {
            s = sorted_src[start + j];
            float4 as = *(const float4*)&a_src[s * 4];
            w.x = __expf(lrelu(as.x + ad.x));
            w.y = __expf(lrelu(as.y + ad.y));
            w.z = __expf(lrelu(as.z + ad.z));
            w.w = __expf(lrelu(as.w + ad.w));
        }
        sbuf[wv][lane] = s;
        *(float4*)&wbuf[wv][lane][0] = w;
        __builtin_amdgcn_wave_barrier();
        int nj8 = (min(64, deg - j0) + 7) & ~7;
        for (int jj = 0; jj < nj8; jj += 8) {
#pragma unroll
            for (int u = 0; u < 8; ++u) {
                int ss = sbuf[wv][jj + u];
                float wh = wbuf[wv][jj + u][head];   // padded lanes have w=0
                den += wh;
                uint32 hv = hb32[(size_t)ss * 64 + lane];
                acc0 += wh * bflo(hv);
                acc1 += wh * bfhi(hv);
            }
        }
        __builtin_amdgcn_wave_barrier();
    }
    float rden = 1.f / den;
    out1b[(size_t)node * 64 + lane] = packbf(acc0 * rden, acc1 * rden);
}

// ---------------- GIN aggregate ----------------
__global__ __launch_bounds__(256) void k_gin_agg(const uint32* __restrict__ ob32,
                                                 const int* __restrict__ row_ptr,
                                                 const int* __restrict__ sorted_src,
                                                 const float* __restrict__ eps_ptr,
                                                 uint32* __restrict__ zb32) {
    __shared__ int sbuf[4][64];
    __shared__ float mbuf[4][64];
    int lane = threadIdx.x & 63, wv = threadIdx.x >> 6;
    int node = blockIdx.x * 4 + wv;
    int start = row_ptr[node];
    int deg = row_ptr[node + 1] - start;
    float acc0 = 0.f, acc1 = 0.f;
    if (deg > 0) {
        for (int j0 = 0; j0 < deg; j0 += 64) {
            int j = j0 + lane;
            int s = 0;
            float m = 0.f;
            if (j < deg) { s = sorted_src[start + j]; m = 1.f; }
            sbuf[wv][lane] = s;
            mbuf[wv][lane] = m;
            __builtin_amdgcn_wave_barrier();
            int nj8 = (min(64, deg - j0) + 7) & ~7;
            for (int jj = 0; jj < nj8; jj += 8) {
#pragma unroll
                for (int u = 0; u < 8; ++u) {
                    int ss = sbuf[wv][jj + u];
                    float mm = mbuf[wv][jj + u];
                    uint32 hv = ob32[(size_t)ss * 64 + lane];
                    acc0 += mm * bflo(hv);
                    acc1 += mm * bfhi(hv);
                }
            }
            __builtin_amdgcn_wave_barrier();
        }
    }
    float ep = 1.f + eps_ptr[0];
    uint32 own = ob32[(size_t)node * 64 + lane];
    zb32[(size_t)node * 64 + lane] = packbf(ep * bflo(own) + acc0, ep * bfhi(own) + acc1);
}

// ---------------- BN stats (bf16 input) ----------------
__global__ __launch_bounds__(256) void k_bnstats_bf16(const uint32* __restrict__ buf,
                                                      float* __restrict__ acc) {
    __shared__ float sh[4][64][4];
    int lane = threadIdx.x & 63, grp = threadIdx.x >> 6;
    float s0 = 0.f, s1 = 0.f, q0 = 0.f, q1 = 0.f;
    for (int r = blockIdx.x * 4 + grp; r < N_NODES; r += gridDim.x * 4) {
        uint32 v = buf[(size_t)r * 64 + lane];
        float v0 = bflo(v), v1 = bfhi(v);
        s0 += v0; s1 += v1; q0 += v0 * v0; q1 += v1 * v1;
    }
    sh[grp][lane][0] = s0; sh[grp][lane][1] = s1;
    sh[grp][lane][2] = q0; sh[grp][lane][3] = q1;
    __syncthreads();
    if (grp == 0) {
#pragma unroll
        for (int g = 1; g < 4; ++g) {
            s0 += sh[g][lane][0]; s1 += sh[g][lane][1];
            q0 += sh[g][lane][2]; q1 += sh[g][lane][3];
        }
        int c0 = lane * 2;
        atomicAdd(&acc[c0], s0);
        atomicAdd(&acc[c0 + 1], s1);
        atomicAdd(&acc[128 + c0], q0);
        atomicAdd(&acc[128 + c0 + 1], q1);
    }
}

__global__ void k_bnparams(const float* __restrict__ acc, const float* __restrict__ gamma,
                           const float* __restrict__ beta, float* __restrict__ ss) {
    int c = threadIdx.x;
    if (c < 128) {
        float mu = acc[c] * (1.f / N_NODES);
        float var = acc[128 + c] * (1.f / N_NODES) - mu * mu;
        float rs = rsqrtf(var + BN_EPS);
        float sc = rs * gamma[c];
        ss[c] = sc;
        ss[128 + c] = beta[c] - mu * sc;
    }
}

// ---------------- BN + ELU in-place on bf16 buffer ----------------
__global__ __launch_bounds__(256) void k_bn_elu_b16(uint32* __restrict__ buf,
                                                    const float* __restrict__ ss) {
    size_t i = (size_t)blockIdx.x * 256 + threadIdx.x;  // uint32 index (2 ch)
    if (i >= (size_t)N_NODES * 64) return;
    int c0 = (int)(i & 63) * 2;
    uint32 v = buf[i];
    float r0 = bflo(v) * ss[c0] + ss[128 + c0];
    float r1 = bfhi(v) * ss[c0 + 1] + ss[128 + c0 + 1];
    r0 = r0 > 0.f ? r0 : __expf(r0) - 1.f;
    r1 = r1 > 0.f ? r1 : __expf(r1) - 1.f;
    buf[i] = packbf(r0, r1);
}

// ---------------- BN + ELU: bf16 in -> fp32 out (final) ----------------
__global__ __launch_bounds__(256) void k_bn_elu_out(const uint32* __restrict__ in,
                                                    const float* __restrict__ ss,
                                                    float2* __restrict__ out) {
    size_t i = (size_t)blockIdx.x * 256 + threadIdx.x;  // uint32 index (2 ch)
    if (i >= (size_t)N_NODES * 64) return;
    int c0 = (int)(i & 63) * 2;
    uint32 v = in[i];
    float r0 = bflo(v) * ss[c0] + ss[128 + c0];
    float r1 = bfhi(v) * ss[c0 + 1] + ss[128 + c0 + 1];
    r0 = r0 > 0.f ? r0 : __expf(r0) - 1.f;
    r1 = r1 > 0.f ? r1 : __expf(r1) - 1.f;
    out[i] = make_float2(r0, r1);
}

extern "C" void kernel_launch(void* const* d_in, const int* in_sizes, int n_in,
                              void* d_out, int out_size, void* d_ws, size_t ws_size,
                              hipStream_t stream) {
    (void)in_sizes; (void)n_in; (void)out_size; (void)ws_size;
    const float* x       = (const float*)d_in[0];
    const float* W_gat   = (const float*)d_in[1];
    const float* att_src = (const float*)d_in[2];
    const float* att_dst = (const float*)d_in[3];
    // bias_gat / lin_b cancel exactly under batch-norm -> dropped
    const float* bn1_g   = (const float*)d_in[5];
    const float* bn1_b   = (const float*)d_in[6];
    const float* eps_gin = (const float*)d_in[7];
    const float* lin_W   = (const float*)d_in[8];
    const float* bn2_g   = (const float*)d_in[10];
    const float* bn2_b   = (const float*)d_in[11];
    const int*   ei      = (const int*)d_in[12];
    float* out = (float*)d_out;

    char* w = (char*)d_ws;
    size_t o = 0;
    auto take = [&](size_t b) -> char* {
        char* p = w + o;
        o += (b + 255) & ~(size_t)255;
        return p;
    };
    unsigned short* hb   = (unsigned short*)take((size_t)N_NODES * 128 * 2);
    unsigned short* Wt1  = (unsigned short*)take((size_t)128 * IN_C * 2);
    unsigned short* Wt2  = (unsigned short*)take((size_t)128 * HID * 2);
    uint32* o1b          = (uint32*)take((size_t)N_NODES * 64 * 4);
    float* a_src         = (float*)take((size_t)N_NODES * 4 * 4);
    float* a_dst         = (float*)take((size_t)N_NODES * 4 * 4);
    int*   sorted        = (int*)take((size_t)N_EDGES * 4);
    int*   row_ptr       = (int*)take((size_t)(N_NODES + 1) * 4);
    int*   counts        = (int*)take((size_t)N_NODES * 4);
    int*   cursor        = (int*)take((size_t)N_NODES * 4);
    int*   bsums         = (int*)take(4096);
    int*   boffs         = (int*)take(4096);
    float* bnacc         = (float*)take(512 * 4);
    float* ss1           = (float*)take(256 * 4);
    float* ss2           = (float*)take(256 * 4);
    uint32* zb  = (uint32*)hb;  // reuse: hb dead after k_gat_agg
    uint32* o2b = o1b;          // reuse: o1b dead after k_gin_agg

    const int nScanBlocks = (N_NODES + 1023) / 1024;
    const int nGemmBlocks = (N_NODES + 127) / 128;

    k_init<<<(N_NODES + 255) / 256, 256, 0, stream>>>(counts, cursor, bnacc);
    k_transpose_bf16<<<(IN_C * 128 + 255) / 256, 256, 0, stream>>>(W_gat, Wt1, IN_C);
    k_transpose_bf16<<<(HID * 128 + 255) / 256, 256, 0, stream>>>(lin_W, Wt2, HID);
    k_gemm<true, false><<<nGemmBlocks, 256, 0, stream>>>(x, Wt1, hb, IN_C);
    k_att<<<N_NODES / 2, 256, 0, stream>>>(hb, att_src, att_dst, a_src, a_dst);
    k_hist<<<(N_EDGES + 255) / 256, 256, 0, stream>>>(ei, counts);
    k_scan_a<<<nScanBlocks, 256, 0, stream>>>(counts, row_ptr, bsums);
    k_scan_b<<<1, 64, 0, stream>>>(bsums, boffs, row_ptr, nScanBlocks);
    k_scan_c<<<nScanBlocks, 256, 0, stream>>>(row_ptr, boffs);
    k_scatter<<<2048, 256, 0, stream>>>(ei, row_ptr, cursor, sorted);
    k_gat_agg<<<N_NODES / 4, 256, 0, stream>>>((const uint32*)hb, a_src, a_dst, row_ptr,
                                               sorted, o1b);
    k_bnstats_bf16<<<512, 256, 0, stream>>>(o1b, bnacc);
    k_bnparams<<<1, 128, 0, stream>>>(bnacc, bn1_g, bn1_b, ss1);
    k_bn_elu_b16<<<(N_NODES * 64 + 255) / 256, 256, 0, stream>>>(o1b, ss1);
    k_gin_agg<<<N_NODES / 4, 256, 0, stream>>>(o1b, row_ptr, sorted, eps_gin, zb);
    k_gemm<false, false><<<nGemmBlocks, 256, 0, stream>>>(zb, Wt2, o2b, HID);
    k_bnstats_bf16<<<512, 256, 0, stream>>>(o2b, bnacc + 256);
    k_bnparams<<<1, 128, 0, stream>>>(bnacc + 256, bn2_g, bn2_b, ss2);
    k_bn_elu_out<<<(N_NODES * 64 + 255) / 256, 256, 0, stream>>>(o2b, ss2, (float2*)out);
}

// Round 5
// 542.409 us; speedup vs baseline: 1.7193x; 1.1711x over previous
//
#include <hip/hip_runtime.h>

#define N_NODES 100000
#define N_EDGES 1600000
#define IN_C 256
#define HID 128
#define NEG_SLOPE 0.2f
#define BN_EPS 1e-5f
#define NBUCK 391          // ceil(N_NODES/256): bucket b covers dst [b*256,(b+1)*256)
#define NPART 391          // ceil(N_EDGES/4096) partition tiles

typedef unsigned int uint32;
typedef __attribute__((ext_vector_type(8))) short bf16x8;
typedef __attribute__((ext_vector_type(4))) float f32x4;

__device__ __forceinline__ float lrelu(float x) { return x > 0.f ? x : NEG_SLOPE * x; }

__device__ __forceinline__ unsigned short f2bf(float f) {
    uint32 u = __float_as_uint(f);
    u += 0x7fffu + ((u >> 16) & 1u);
    return (unsigned short)(u >> 16);
}
__device__ __forceinline__ float bf2f(unsigned short h) {
    return __uint_as_float(((uint32)h) << 16);
}
__device__ __forceinline__ float bflo(uint32 v) { return __uint_as_float(v << 16); }
__device__ __forceinline__ float bfhi(uint32 v) { return __uint_as_float(v & 0xffff0000u); }
__device__ __forceinline__ uint32 packbf(float a, float b) {
    return (uint32)f2bf(a) | ((uint32)f2bf(b) << 16);
}

// ---------------- init ----------------
__global__ void k_init(int* __restrict__ bcount, float* __restrict__ bnacc) {
    int t = threadIdx.x;
    if (t < NBUCK) bcount[t] = 0;
    if (t < 512) bnacc[t] = 0.f;
}

// ---------------- transpose W [K][128] fp32 -> Wt [128][K] bf16 ----------------
__global__ void k_transpose_bf16(const float* __restrict__ W, unsigned short* __restrict__ Wt,
                                 int K) {
    int idx = blockIdx.x * 256 + threadIdx.x;
    if (idx >= K * 128) return;
    int k = idx >> 7, n = idx & 127;
    Wt[n * K + k] = f2bf(W[idx]);
}

// ---------------- MFMA GEMM, register-prefetch pipelined ----------------
template <bool AF32, bool OUTF32>
__global__ __launch_bounds__(256) void k_gemm(const void* __restrict__ Av,
                                              const unsigned short* __restrict__ Wt,
                                              void* __restrict__ Out, int K) {
    __shared__ unsigned short As[128 * 72];
    __shared__ unsigned short Bs[128 * 72];
    const int t = threadIdx.x;
    const int n0 = blockIdx.x * 128;
    const int wv = t >> 6, lane = t & 63;
    const int wy = wv >> 1, wx = wv & 1;
    const int lm = lane & 15, lg = lane >> 4;
    const float* Af = (const float*)Av;
    const unsigned short* Ah = (const unsigned short*)Av;

    f32x4 acc[4][4];
#pragma unroll
    for (int i = 0; i < 4; ++i)
#pragma unroll
        for (int j = 0; j < 4; ++j) acc[i][j] = (f32x4){0.f, 0.f, 0.f, 0.f};

    float4 afp[8];
    uint4 ahp[4];
    uint4 bvp[4];

    // prefetch chunk 0
    if (AF32) {
#pragma unroll
        for (int p = 0; p < 8; ++p) {
            int idx = p * 256 + t, row = idx >> 4, c4 = idx & 15, gn = n0 + row;
            afp[p] = (gn < N_NODES) ? *(const float4*)&Af[(size_t)gn * K + c4 * 4]
                                    : make_float4(0.f, 0.f, 0.f, 0.f);
        }
    } else {
#pragma unroll
        for (int p = 0; p < 4; ++p) {
            int idx = p * 256 + t, row = idx >> 3, c = idx & 7, gn = n0 + row;
            ahp[p] = (gn < N_NODES) ? *(const uint4*)&Ah[(size_t)gn * K + c * 8]
                                    : make_uint4(0, 0, 0, 0);
        }
    }
#pragma unroll
    for (int p = 0; p < 4; ++p) {
        int idx = p * 256 + t, n = idx >> 3, c = idx & 7;
        bvp[p] = *(const uint4*)&Wt[(size_t)n * K + c * 8];
    }

    for (int kc = 0; kc < K; kc += 64) {
        // commit prefetched chunk to LDS
        if (AF32) {
#pragma unroll
            for (int p = 0; p < 8; ++p) {
                int idx = p * 256 + t, row = idx >> 4, c4 = idx & 15;
                ushort4 b;
                b.x = f2bf(afp[p].x); b.y = f2bf(afp[p].y);
                b.z = f2bf(afp[p].z); b.w = f2bf(afp[p].w);
                *(ushort4*)&As[row * 72 + c4 * 4] = b;
            }
        } else {
#pragma unroll
            for (int p = 0; p < 4; ++p) {
                int idx = p * 256 + t, row = idx >> 3, c = idx & 7;
                *(uint4*)&As[row * 72 + c * 8] = ahp[p];
            }
        }
#pragma unroll
        for (int p = 0; p < 4; ++p) {
            int idx = p * 256 + t, n = idx >> 3, c = idx & 7;
            *(uint4*)&Bs[n * 72 + c * 8] = bvp[p];
        }
        __syncthreads();
        // issue next chunk's loads; results consumed next iteration -> overlap MFMA
        int kn = kc + 64;
        if (kn < K) {
            if (AF32) {
#pragma unroll
                for (int p = 0; p < 8; ++p) {
                    int idx = p * 256 + t, row = idx >> 4, c4 = idx & 15, gn = n0 + row;
                    afp[p] = (gn < N_NODES) ? *(const float4*)&Af[(size_t)gn * K + kn + c4 * 4]
                                            : make_float4(0.f, 0.f, 0.f, 0.f);
                }
            } else {
#pragma unroll
                for (int p = 0; p < 4; ++p) {
                    int idx = p * 256 + t, row = idx >> 3, c = idx & 7, gn = n0 + row;
                    ahp[p] = (gn < N_NODES) ? *(const uint4*)&Ah[(size_t)gn * K + kn + c * 8]
                                            : make_uint4(0, 0, 0, 0);
                }
            }
#pragma unroll
            for (int p = 0; p < 4; ++p) {
                int idx = p * 256 + t, n = idx >> 3, c = idx & 7;
                bvp[p] = *(const uint4*)&Wt[(size_t)n * K + kn + c * 8];
            }
        }
#pragma unroll
        for (int ks = 0; ks < 2; ++ks) {
            bf16x8 af[4], bfr[4];
#pragma unroll
            for (int i = 0; i < 4; ++i)
                af[i] = *(const bf16x8*)&As[(wy * 64 + i * 16 + lm) * 72 + ks * 32 + lg * 8];
#pragma unroll
            for (int j = 0; j < 4; ++j)
                bfr[j] = *(const bf16x8*)&Bs[(wx * 64 + j * 16 + lm) * 72 + ks * 32 + lg * 8];
#pragma unroll
            for (int i = 0; i < 4; ++i)
#pragma unroll
                for (int j = 0; j < 4; ++j)
                    acc[i][j] = __builtin_amdgcn_mfma_f32_16x16x32_bf16(af[i], bfr[j],
                                                                        acc[i][j], 0, 0, 0);
        }
        __syncthreads();
    }
#pragma unroll
    for (int i = 0; i < 4; ++i) {
#pragma unroll
        for (int r = 0; r < 4; ++r) {
            int row = n0 + wy * 64 + i * 16 + lg * 4 + r;
            if (row < N_NODES) {
#pragma unroll
                for (int j = 0; j < 4; ++j) {
                    int col = wx * 64 + j * 16 + lm;
                    float v = acc[i][j][r];
                    if (OUTF32) ((float*)Out)[(size_t)row * 128 + col] = v;
                    else ((unsigned short*)Out)[(size_t)row * 128 + col] = f2bf(v);
                }
            }
        }
    }
}

// ---------------- attention coefficients ----------------
__global__ __launch_bounds__(256) void k_att(const unsigned short* __restrict__ hb,
                                             const float* __restrict__ att_s,
                                             const float* __restrict__ att_d,
                                             float* __restrict__ a_src,
                                             float* __restrict__ a_dst) {
    int node = blockIdx.x * 2 + (threadIdx.x >> 7);
    int c = threadIdx.x & 127;
    float hv = bf2f(hb[(size_t)node * 128 + c]);
    float ps = hv * att_s[c];
    float pd = hv * att_d[c];
#pragma unroll
    for (int m = 1; m < 32; m <<= 1) {
        ps += __shfl_xor(ps, m);
        pd += __shfl_xor(pd, m);
    }
    if ((c & 31) == 0) {
        int head = c >> 5;
        a_src[node * 4 + head] = ps;
        a_dst[node * 4 + head] = pd;
    }
}

// ---------------- CSR build: two-phase bucket sort ----------------
// Phase 0: per-bucket edge counts
__global__ __launch_bounds__(256) void k_bucket_count(const int* __restrict__ ei,
                                                      int* __restrict__ bcount) {
    __shared__ int hist[NBUCK];
    for (int i = threadIdx.x; i < NBUCK; i += 256) hist[i] = 0;
    __syncthreads();
    for (int e = blockIdx.x * 256 + threadIdx.x; e < N_EDGES; e += gridDim.x * 256)
        atomicAdd(&hist[ei[N_EDGES + e] >> 8], 1);
    __syncthreads();
    for (int i = threadIdx.x; i < NBUCK; i += 256)
        if (hist[i]) atomicAdd(&bcount[i], hist[i]);
}

// Phase 0b: exclusive scan of bucket counts -> bucket_base, init gcursor
__global__ void k_bucket_scan(const int* __restrict__ bcount, int* __restrict__ bucket_base,
                              int* __restrict__ gcursor, int* __restrict__ row_ptr) {
    __shared__ int sh[512];
    int t = threadIdx.x;
    int v0 = (t < NBUCK) ? bcount[t] : 0;
    int val = v0;
    sh[t] = val;
    __syncthreads();
    for (int off = 1; off < 512; off <<= 1) {
        int o = (t >= off) ? sh[t - off] : 0;
        __syncthreads();
        val += o;
        sh[t] = val;
        __syncthreads();
    }
    if (t < NBUCK) {
        int e = val - v0;
        bucket_base[t] = e;
        gcursor[t] = e;
    }
    if (t == 0) {
        bucket_base[NBUCK] = N_EDGES;
        row_ptr[N_NODES] = N_EDGES;
    }
}

// Phase A: partition edges into bucket regions (packed dlocal|src), LDS-ranked
__global__ __launch_bounds__(256) void k_partition(const int* __restrict__ ei,
                                                   int* __restrict__ gcursor,
                                                   int* __restrict__ staging) {
    __shared__ int hist[NBUCK];
    __shared__ int base[NBUCK];
    int t = threadIdx.x;
    int e0 = blockIdx.x * 4096;
    for (int i = t; i < NBUCK; i += 256) hist[i] = 0;
    __syncthreads();
    int pk[16], cb[16];
#pragma unroll
    for (int u = 0; u < 16; ++u) {
        int e = e0 + u * 256 + t;
        cb[u] = -1;
        if (e < N_EDGES) {
            int s = ei[e], d = ei[N_EDGES + e];
            int b = d >> 8;
            int r = atomicAdd(&hist[b], 1);     // rank within (block, bucket)
            pk[u] = ((d & 255) << 17) | s;      // src<2^17, dlocal<256
            cb[u] = (r << 9) | b;               // b<512, r<4096
        }
    }
    __syncthreads();
    for (int i = t; i < NBUCK; i += 256)
        if (hist[i]) base[i] = atomicAdd(&gcursor[i], hist[i]);
    __syncthreads();
#pragma unroll
    for (int u = 0; u < 16; ++u) {
        if (cb[u] >= 0) {
            int b = cb[u] & 511, r = cb[u] >> 9;
            staging[base[b] + r] = pk[u];
        }
    }
}

// Phase B: per-bucket counting sort by dst; emits row_ptr + sorted_src.
// One block per bucket -> scatter region (~16KB) stays in one XCD's L2.
__global__ __launch_bounds__(256) void k_bucket_sort(const int* __restrict__ staging,
                                                     const int* __restrict__ bucket_base,
                                                     int* __restrict__ row_ptr,
                                                     int* __restrict__ sorted_src) {
    __shared__ int hist[256];
    __shared__ int sh[256];
    int t = threadIdx.x, b = blockIdx.x;
    int lo = bucket_base[b], hi = bucket_base[b + 1];
    hist[t] = 0;
    __syncthreads();
    for (int i = lo + t; i < hi; i += 256) atomicAdd(&hist[staging[i] >> 17], 1);
    __syncthreads();
    int v0 = hist[t];
    int val = v0;
    sh[t] = val;
    __syncthreads();
    for (int off = 1; off < 256; off <<= 1) {
        int o = (t >= off) ? sh[t - off] : 0;
        __syncthreads();
        val += o;
        sh[t] = val;
        __syncthreads();
    }
    int excl = val - v0;
    int d = b * 256 + t;
    if (d < N_NODES) row_ptr[d] = lo + excl;
    hist[t] = excl;  // becomes running cursor
    __syncthreads();
    for (int i = lo + t; i < hi; i += 256) {
        int p = staging[i];
        int r = atomicAdd(&hist[p >> 17], 1);
        sorted_src[lo + r] = p & 0x1FFFF;
    }
}

// ---------------- GAT aggregate: single pass, deferred normalization ----------------
__global__ __launch_bounds__(256) void k_gat_agg(const uint32* __restrict__ hb32,
                                                 const float* __restrict__ a_src,
                                                 const float* __restrict__ a_dst,
                                                 const int* __restrict__ row_ptr,
                                                 const int* __restrict__ sorted_src,
                                                 uint32* __restrict__ out1b) {
    __shared__ int sbuf[4][64];
    __shared__ float wbuf[4][64][4];
    int lane = threadIdx.x & 63, wv = threadIdx.x >> 6;
    int node = blockIdx.x * 4 + wv;
    int start = row_ptr[node];
    int deg = row_ptr[node + 1] - start;
    if (deg == 0) {
        out1b[(size_t)node * 64 + lane] = 0u;
        return;
    }
    int head = lane >> 4;
    float4 ad = *(const float4*)&a_dst[node * 4];
    float acc0 = 0.f, acc1 = 0.f, den = 0.f;
    for (int j0 = 0; j0 < deg; j0 += 64) {
        int j = j0 + lane;
        int s = 0;
        float4 w = make_float4(0.f, 0.f, 0.f, 0.f);
        if (j < deg) {
            s = sorted_src[start + j];
            float4 as = *(const float4*)&a_src[s * 4];
            w.x = __expf(lrelu(as.x + ad.x));
            w.y = __expf(lrelu(as.y + ad.y));
            w.z = __expf(lrelu(as.z + ad.z));
            w.w = __expf(lrelu(as.w + ad.w));
        }
        sbuf[wv][lane] = s;
        *(float4*)&wbuf[wv][lane][0] = w;
        __builtin_amdgcn_wave_barrier();
        int nj8 = (min(64, deg - j0) + 7) & ~7;
        for (int jj = 0; jj < nj8; jj += 8) {
#pragma unroll
            for (int u = 0; u < 8; ++u) {
                int ss = sbuf[wv][jj + u];
                float wh = wbuf[wv][jj + u][head];  // padded lanes have w=0
                den += wh;
                uint32 hv = hb32[(size_t)ss * 64 + lane];
                acc0 += wh * bflo(hv);
                acc1 += wh * bfhi(hv);
            }
        }
        __builtin_amdgcn_wave_barrier();
    }
    float rden = 1.f / den;
    out1b[(size_t)node * 64 + lane] = packbf(acc0 * rden, acc1 * rden);
}

// ---------------- GIN aggregate ----------------
__global__ __launch_bounds__(256) void k_gin_agg(const uint32* __restrict__ ob32,
                                                 const int* __restrict__ row_ptr,
                                                 const int* __restrict__ sorted_src,
                                                 const float* __restrict__ eps_ptr,
                                                 uint32* __restrict__ zb32) {
    __shared__ int sbuf[4][64];
    __shared__ float mbuf[4][64];
    int lane = threadIdx.x & 63, wv = threadIdx.x >> 6;
    int node = blockIdx.x * 4 + wv;
    int start = row_ptr[node];
    int deg = row_ptr[node + 1] - start;
    float acc0 = 0.f, acc1 = 0.f;
    if (deg > 0) {
        for (int j0 = 0; j0 < deg; j0 += 64) {
            int j = j0 + lane;
            int s = 0;
            float m = 0.f;
            if (j < deg) { s = sorted_src[start + j]; m = 1.f; }
            sbuf[wv][lane] = s;
            mbuf[wv][lane] = m;
            __builtin_amdgcn_wave_barrier();
            int nj8 = (min(64, deg - j0) + 7) & ~7;
            for (int jj = 0; jj < nj8; jj += 8) {
#pragma unroll
                for (int u = 0; u < 8; ++u) {
                    int ss = sbuf[wv][jj + u];
                    float mm = mbuf[wv][jj + u];
                    uint32 hv = ob32[(size_t)ss * 64 + lane];
                    acc0 += mm * bflo(hv);
                    acc1 += mm * bfhi(hv);
                }
            }
            __builtin_amdgcn_wave_barrier();
        }
    }
    float ep = 1.f + eps_ptr[0];
    uint32 own = ob32[(size_t)node * 64 + lane];
    zb32[(size_t)node * 64 + lane] = packbf(ep * bflo(own) + acc0, ep * bfhi(own) + acc1);
}

// ---------------- BN stats (bf16 input) ----------------
__global__ __launch_bounds__(256) void k_bnstats_bf16(const uint32* __restrict__ buf,
                                                      float* __restrict__ acc) {
    __shared__ float sh[4][64][4];
    int lane = threadIdx.x & 63, grp = threadIdx.x >> 6;
    float s0 = 0.f, s1 = 0.f, q0 = 0.f, q1 = 0.f;
    for (int r = blockIdx.x * 4 + grp; r < N_NODES; r += gridDim.x * 4) {
        uint32 v = buf[(size_t)r * 64 + lane];
        float v0 = bflo(v), v1 = bfhi(v);
        s0 += v0; s1 += v1; q0 += v0 * v0; q1 += v1 * v1;
    }
    sh[grp][lane][0] = s0; sh[grp][lane][1] = s1;
    sh[grp][lane][2] = q0; sh[grp][lane][3] = q1;
    __syncthreads();
    if (grp == 0) {
#pragma unroll
        for (int g = 1; g < 4; ++g) {
            s0 += sh[g][lane][0]; s1 += sh[g][lane][1];
            q0 += sh[g][lane][2]; q1 += sh[g][lane][3];
        }
        int c0 = lane * 2;
        atomicAdd(&acc[c0], s0);
        atomicAdd(&acc[c0 + 1], s1);
        atomicAdd(&acc[128 + c0], q0);
        atomicAdd(&acc[128 + c0 + 1], q1);
    }
}

__global__ void k_bnparams(const float* __restrict__ acc, const float* __restrict__ gamma,
                           const float* __restrict__ beta, float* __restrict__ ss) {
    int c = threadIdx.x;
    if (c < 128) {
        float mu = acc[c] * (1.f / N_NODES);
        float var = acc[128 + c] * (1.f / N_NODES) - mu * mu;
        float rs = rsqrtf(var + BN_EPS);
        float sc = rs * gamma[c];
        ss[c] = sc;
        ss[128 + c] = beta[c] - mu * sc;
    }
}

// ---------------- BN + ELU in-place on bf16 buffer ----------------
__global__ __launch_bounds__(256) void k_bn_elu_b16(uint32* __restrict__ buf,
                                                    const float* __restrict__ ss) {
    size_t i = (size_t)blockIdx.x * 256 + threadIdx.x;
    if (i >= (size_t)N_NODES * 64) return;
    int c0 = (int)(i & 63) * 2;
    uint32 v = buf[i];
    float r0 = bflo(v) * ss[c0] + ss[128 + c0];
    float r1 = bfhi(v) * ss[c0 + 1] + ss[128 + c0 + 1];
    r0 = r0 > 0.f ? r0 : __expf(r0) - 1.f;
    r1 = r1 > 0.f ? r1 : __expf(r1) - 1.f;
    buf[i] = packbf(r0, r1);
}

// ---------------- BN + ELU: bf16 in -> fp32 out (final) ----------------
__global__ __launch_bounds__(256) void k_bn_elu_out(const uint32* __restrict__ in,
                                                    const float* __restrict__ ss,
                                                    float2* __restrict__ out) {
    size_t i = (size_t)blockIdx.x * 256 + threadIdx.x;
    if (i >= (size_t)N_NODES * 64) return;
    int c0 = (int)(i & 63) * 2;
    uint32 v = in[i];
    float r0 = bflo(v) * ss[c0] + ss[128 + c0];
    float r1 = bfhi(v) * ss[c0 + 1] + ss[128 + c0 + 1];
    r0 = r0 > 0.f ? r0 : __expf(r0) - 1.f;
    r1 = r1 > 0.f ? r1 : __expf(r1) - 1.f;
    out[i] = make_float2(r0, r1);
}

extern "C" void kernel_launch(void* const* d_in, const int* in_sizes, int n_in,
                              void* d_out, int out_size, void* d_ws, size_t ws_size,
                              hipStream_t stream) {
    (void)in_sizes; (void)n_in; (void)out_size; (void)ws_size;
    const float* x       = (const float*)d_in[0];
    const float* W_gat   = (const float*)d_in[1];
    const float* att_src = (const float*)d_in[2];
    const float* att_dst = (const float*)d_in[3];
    // bias_gat / lin_b cancel exactly under batch-norm -> dropped
    const float* bn1_g   = (const float*)d_in[5];
    const float* bn1_b   = (const float*)d_in[6];
    const float* eps_gin = (const float*)d_in[7];
    const float* lin_W   = (const float*)d_in[8];
    const float* bn2_g   = (const float*)d_in[10];
    const float* bn2_b   = (const float*)d_in[11];
    const int*   ei      = (const int*)d_in[12];
    float* out = (float*)d_out;

    char* w = (char*)d_ws;
    size_t o = 0;
    auto take = [&](size_t b) -> char* {
        char* p = w + o;
        o += (b + 255) & ~(size_t)255;
        return p;
    };
    unsigned short* hb   = (unsigned short*)take((size_t)N_NODES * 128 * 2);
    unsigned short* Wt1  = (unsigned short*)take((size_t)128 * IN_C * 2);
    unsigned short* Wt2  = (unsigned short*)take((size_t)128 * HID * 2);
    uint32* o1b          = (uint32*)take((size_t)N_NODES * 64 * 4);
    float* a_src         = (float*)take((size_t)N_NODES * 4 * 4);
    float* a_dst         = (float*)take((size_t)N_NODES * 4 * 4);
    int*   sorted        = (int*)take((size_t)N_EDGES * 4);
    int*   staging       = (int*)take((size_t)N_EDGES * 4);
    int*   row_ptr       = (int*)take((size_t)(N_NODES + 1) * 4);
    int*   bcount        = (int*)take((NBUCK + 1) * 4);
    int*   bucket_base   = (int*)take((NBUCK + 1) * 4);
    int*   gcursor       = (int*)take((NBUCK + 1) * 4);
    float* bnacc         = (float*)take(512 * 4);
    float* ss1           = (float*)take(256 * 4);
    float* ss2           = (float*)take(256 * 4);
    uint32* zb  = (uint32*)hb;  // reuse: hb dead after k_gat_agg
    uint32* o2b = o1b;          // reuse: o1b dead after k_gin_agg

    const int nGemmBlocks = (N_NODES + 127) / 128;

    k_init<<<1, 512, 0, stream>>>(bcount, bnacc);
    k_transpose_bf16<<<(IN_C * 128 + 255) / 256, 256, 0, stream>>>(W_gat, Wt1, IN_C);
    k_transpose_bf16<<<(HID * 128 + 255) / 256, 256, 0, stream>>>(lin_W, Wt2, HID);
    k_gemm<true, false><<<nGemmBlocks, 256, 0, stream>>>(x, Wt1, hb, IN_C);
    k_att<<<N_NODES / 2, 256, 0, stream>>>(hb, att_src, att_dst, a_src, a_dst);
    k_bucket_count<<<256, 256, 0, stream>>>(ei, bcount);
    k_bucket_scan<<<1, 512, 0, stream>>>(bcount, bucket_base, gcursor, row_ptr);
    k_partition<<<NPART, 256, 0, stream>>>(ei, gcursor, staging);
    k_bucket_sort<<<NBUCK, 256, 0, stream>>>(staging, bucket_base, row_ptr, sorted);
    k_gat_agg<<<N_NODES / 4, 256, 0, stream>>>((const uint32*)hb, a_src, a_dst, row_ptr,
                                               sorted, o1b);
    k_bnstats_bf16<<<512, 256, 0, stream>>>(o1b, bnacc);
    k_bnparams<<<1, 128, 0, stream>>>(bnacc, bn1_g, bn1_b, ss1);
    k_bn_elu_b16<<<(N_NODES * 64 + 255) / 256, 256, 0, stream>>>(o1b, ss1);
    k_gin_agg<<<N_NODES / 4, 256, 0, stream>>>(o1b, row_ptr, sorted, eps_gin, zb);
    k_gemm<false, false><<<nGemmBlocks, 256, 0, stream>>>(zb, Wt2, o2b, HID);
    k_bnstats_bf16<<<512, 256, 0, stream>>>(o2b, bnacc + 256);
    k_bnparams<<<1, 128, 0, stream>>>(bnacc + 256, bn2_g, bn2_b, ss2);
    k_bn_elu_out<<<(N_NODES * 64 + 255) / 256, 256, 0, stream>>>(o2b, ss2, (float2*)out);
}